// Round 1
// baseline (868.397 us; speedup 1.0000x reference)
//
#include <hip/hip_runtime.h>
#include <math.h>

#define NN    4096
#define NPP   1024
#define KDEG  8
#define BN    8192     // BS*N
#define NE    65536    // BN*KDEG

// ---------------------------------------------------------------------------
// Kernel 1: three_nn + inverse-d^2 interpolation; builds concatenated features
//   h0c [BN][32]      (ch 0..15 = interp(uph0), ch 16..31 = h0)
//   h1c [BN][32][3]   (ch 0..15 = interp(uph1), ch 16..31 = h1)
// ---------------------------------------------------------------------------
__global__ __launch_bounds__(256) void interp_kernel(
    const float* __restrict__ h0, const float* __restrict__ h1,
    const float* __restrict__ uph0, const float* __restrict__ uph1,
    const float* __restrict__ xyz, const float* __restrict__ xyzp,
    float* __restrict__ h0c, float* __restrict__ h1c)
{
  __shared__ float cxs[NPP], cys[NPP], czs[NPP];
  const int tid = threadIdx.x;
  const int fi  = blockIdx.x * 256 + tid;   // fine index, block stays in one batch
  const int b   = fi >> 12;                 // N = 4096
  for (int j = tid; j < NPP; j += 256) {
    cxs[j] = xyzp[(b*NPP + j)*3 + 0];
    cys[j] = xyzp[(b*NPP + j)*3 + 1];
    czs[j] = xyzp[(b*NPP + j)*3 + 2];
  }
  __syncthreads();
  const float px = xyz[fi*3+0], py = xyz[fi*3+1], pz = xyz[fi*3+2];
  float d0 = 3.4e38f, d1 = 3.4e38f, d2 = 3.4e38f;
  int   i0 = 0, i1 = 0, i2 = 0;
  for (int j = 0; j < NPP; ++j) {
    float ax = px - cxs[j], ay = py - cys[j], az = pz - czs[j];
    float dd = ax*ax + ay*ay + az*az;
    if (dd < d0)      { d2=d1; i2=i1; d1=d0; i1=i0; d0=dd; i0=j; }
    else if (dd < d1) { d2=d1; i2=i1; d1=dd; i1=j; }
    else if (dd < d2) { d2=dd; i2=j; }
  }
  float w0, w1v, w2v;
  {
    float s0 = sqrtf(fmaxf(d0, 0.f));
    float s1 = sqrtf(fmaxf(d1, 0.f));
    float s2 = sqrtf(fmaxf(d2, 0.f));
    w0  = 1.f / (fmaxf(s0*s0, 1e-10f) + 1e-8f);
    w1v = 1.f / (fmaxf(s1*s1, 1e-10f) + 1e-8f);
    w2v = 1.f / (fmaxf(s2*s2, 1e-10f) + 1e-8f);
    float wsum = w0 + w1v + w2v;
    w0 /= wsum; w1v /= wsum; w2v /= wsum;
  }
  const float* u0 = uph0 + (size_t)b*NPP*16;
  const float* u1 = uph1 + (size_t)b*NPP*48;
  #pragma unroll
  for (int c = 0; c < 16; ++c) {
    h0c[(size_t)fi*32 + c]      = w0*u0[i0*16+c] + w1v*u0[i1*16+c] + w2v*u0[i2*16+c];
    h0c[(size_t)fi*32 + 16 + c] = h0[(size_t)fi*16 + c];
  }
  #pragma unroll
  for (int q = 0; q < 48; ++q) {
    h1c[(size_t)fi*96 + q]      = w0*u1[i0*48+q] + w1v*u1[i1*48+q] + w2v*u1[i2*48+q];
    h1c[(size_t)fi*96 + 48 + q] = h1[(size_t)fi*48 + q];
  }
}

// ---------------------------------------------------------------------------
// Kernel 2: radial MLPs + CG-basis messages + mean aggregation over K=8 edges.
// 32 edges / block (= 4 dst nodes, since edge_dst = e>>3 by construction).
// Thread = (edge eL = tid&31, channel pair o2 = tid>>5 -> o2 and o2+8).
// w3 staged in 8-row (16KB) LDS chunks; LDS reads of w3 are wave-broadcast.
// ---------------------------------------------------------------------------
struct MsgParams {
  const float* r;
  const int*   src;
  const float* b00; const float* b01; const float* b10; const float* b11;
  const float* w1[4]; const float* b1a[4];
  const float* w2[4]; const float* b2a[4];
  const float* w3[4];
  const float* h0c; const float* h1c;
  float* agg0; float* agg1;
};

__global__ __launch_bounds__(256) void msg_kernel(MsgParams P)
{
  __shared__ float sw3[8][512];     // 16 KB, one k-chunk of w3
  __shared__ float sX[32][33];      // x2 (MLP output) per edge, padded
  __shared__ float shs0[32][33];    // h0c[src], padded
  __shared__ float shs1[32][96];    // h1c[src]
  __shared__ float sb00[32];
  __shared__ float sb01[32][3];
  __shared__ float sb10[32][3];
  __shared__ float sb11[32][27];
  __shared__ float srr[32];
  __shared__ float smsg0[32][17];   // padded
  __shared__ float smsg1[32][49];   // padded
  __shared__ float stmp[32][97];    // tmp contraction, padded

  const int tid = threadIdx.x;
  const int e0  = blockIdx.x * 32;
  const int eL  = tid & 31;
  const int o2  = tid >> 5;         // 0..7

  if (tid < 32) { srr[tid] = P.r[e0+tid]; sb00[tid] = P.b00[e0+tid]; }
  for (int idx = tid; idx < 96; idx += 256) {
    sb01[idx/3][idx%3] = P.b01[e0*3+idx];
    sb10[idx/3][idx%3] = P.b10[e0*3+idx];
  }
  for (int idx = tid; idx < 864; idx += 256)
    sb11[idx/27][idx%27] = P.b11[e0*27+idx];
  for (int idx = tid; idx < 1024; idx += 256) {
    int e = idx >> 5, i = idx & 31;
    shs0[e][i] = P.h0c[(size_t)P.src[e0+e]*32 + i];
  }
  for (int idx = tid; idx < 3072; idx += 256) {
    int e = idx / 96, c = idx % 96;
    shs1[e][c] = P.h1c[(size_t)P.src[e0+e]*96 + c];
  }

  // phases: 0 = path00, 1 = path01, 2 = path10, 3..5 = path11 f-slices 0..2
  for (int ph = 0; ph < 6; ++ph) {
    const int p = ph < 3 ? ph : 3;
    const int f = ph < 3 ? 0 : ph - 3;
    const float* w3 = P.w3[p];

    __syncthreads();   // prior-phase C/E readers done before we rewrite sX/stmp/sw3

    if (ph <= 3) {     // radial MLP for this path (path11 reused for f=1,2)
      const float* w1  = P.w1[p];  const float* bb1 = P.b1a[p];
      const float* w2  = P.w2[p];  const float* bb2 = P.b2a[p];
      const float rv = srr[eL];
      float x1[32];
      #pragma unroll
      for (int k = 0; k < 32; ++k) x1[k] = fmaxf(fmaf(rv, w1[k], bb1[k]), 0.f);
      #pragma unroll
      for (int t = 0; t < 4; ++t) {
        int j = o2*4 + t;
        float acc = bb2[j];
        #pragma unroll
        for (int k = 0; k < 32; ++k) acc = fmaf(x1[k], w2[k*32+j], acc);
        sX[eL][j] = fmaxf(acc, 0.f);
      }
    }
    if (ph == 2) {                       // tmp[i] = sum_n b10[n] * hs1[i][n]
      for (int idx = tid; idx < 1024; idx += 256) {
        int e = idx >> 5, i = idx & 31;
        stmp[e][i] = sb10[e][0]*shs1[e][i*3+0]
                   + sb10[e][1]*shs1[e][i*3+1]
                   + sb10[e][2]*shs1[e][i*3+2];
      }
    } else if (ph >= 3) {                // tmp[i][m] = sum_n b11[m][n][f] * hs1[i][n]
      for (int idx = tid; idx < 3072; idx += 256) {
        int e = idx / 96, rem = idx % 96;
        int i = rem / 3, m = rem % 3;
        float a = 0.f;
        #pragma unroll
        for (int n = 0; n < 3; ++n)
          a = fmaf(sb11[e][(m*3+n)*3+f], shs1[e][i*3+n], a);
        stmp[e][i*3+m] = a;
      }
    }

    float R0[32], R1[32];
    #pragma unroll
    for (int i = 0; i < 32; ++i) { R0[i] = 0.f; R1[i] = 0.f; }

    for (int q = 0; q < 4; ++q) {        // 4 k-chunks of 8 rows
      if (q > 0) __syncthreads();        // prior chunk's readers done
      if (ph < 3) {
        for (int idx = tid; idx < 4096; idx += 256)
          (&sw3[0][0])[idx] = w3[q*4096 + idx];
      } else {
        for (int idx = tid; idx < 4096; idx += 256)
          (&sw3[0][0])[idx] = w3[(q*4096 + idx)*3 + f];
      }
      __syncthreads();
      #pragma unroll 2
      for (int kk = 0; kk < 8; ++kk) {
        float xk = sX[eL][q*8 + kk];
        const float* rowA = &sw3[kk][o2*32];
        const float* rowB = rowA + 256;  // (o2+8)*32
        #pragma unroll
        for (int i = 0; i < 32; ++i) {
          R0[i] = fmaf(xk, rowA[i], R0[i]);
          R1[i] = fmaf(xk, rowB[i], R1[i]);
        }
      }
    }

    // contraction with the per-edge tmp tensors
    const int oA = o2, oB = o2 + 8;
    if (ph == 0) {
      float s0 = 0.f, s1 = 0.f;
      #pragma unroll
      for (int i = 0; i < 32; ++i) {
        float hv = shs0[eL][i];
        s0 = fmaf(R0[i], hv, s0); s1 = fmaf(R1[i], hv, s1);
      }
      float bb = sb00[eL];
      smsg0[eL][oA] = bb * s0;
      smsg0[eL][oB] = bb * s1;
    } else if (ph == 1) {
      float s0 = 0.f, s1 = 0.f;
      #pragma unroll
      for (int i = 0; i < 32; ++i) {
        float hv = shs0[eL][i];
        s0 = fmaf(R0[i], hv, s0); s1 = fmaf(R1[i], hv, s1);
      }
      #pragma unroll
      for (int m = 0; m < 3; ++m) {
        float bm = sb01[eL][m];
        smsg1[eL][oA*3+m] = bm * s0;
        smsg1[eL][oB*3+m] = bm * s1;
      }
    } else if (ph == 2) {
      float s0 = 0.f, s1 = 0.f;
      #pragma unroll
      for (int i = 0; i < 32; ++i) {
        float tv = stmp[eL][i];
        s0 = fmaf(R0[i], tv, s0); s1 = fmaf(R1[i], tv, s1);
      }
      smsg0[eL][oA] += s0;
      smsg0[eL][oB] += s1;
    } else {
      float a0[3] = {0.f,0.f,0.f}, a1[3] = {0.f,0.f,0.f};
      #pragma unroll
      for (int i = 0; i < 32; ++i) {
        float r0 = R0[i], r1 = R1[i];
        #pragma unroll
        for (int m = 0; m < 3; ++m) {
          float tv = stmp[eL][i*3+m];
          a0[m] = fmaf(r0, tv, a0[m]);
          a1[m] = fmaf(r1, tv, a1[m]);
        }
      }
      #pragma unroll
      for (int m = 0; m < 3; ++m) {
        smsg1[eL][oA*3+m] += a0[m];
        smsg1[eL][oB*3+m] += a1[m];
      }
    }
  }

  __syncthreads();
  // mean over the 8 edges of each of the block's 4 dst nodes
  const int d0n = e0 >> 3;
  if (tid < 64) {
    int dd = tid >> 4, o = tid & 15;
    float s = 0.f;
    #pragma unroll
    for (int j = 0; j < 8; ++j) s += smsg0[dd*8+j][o];
    P.agg0[(size_t)(d0n+dd)*16 + o] = s * 0.125f;
  } else {
    int t = tid - 64;                  // 0..191
    int dd = t / 48, rem = t % 48;
    float s = 0.f;
    #pragma unroll
    for (int j = 0; j < 8; ++j) s += smsg1[dd*8+j][rem];
    P.agg1[(size_t)(d0n+dd)*48 + rem] = s * 0.125f;
  }
}

// ---------------------------------------------------------------------------
// Kernel 3: self-interaction + GNormSE3 for both degrees; writes final output.
// ---------------------------------------------------------------------------
__global__ __launch_bounds__(256) void gnorm_kernel(
    const float* __restrict__ agg0, const float* __restrict__ agg1,
    const float* __restrict__ h0c, const float* __restrict__ h1c,
    const float* __restrict__ ws0, const float* __restrict__ ws1,
    const float* __restrict__ g0, const float* __restrict__ be0,
    const float* __restrict__ g1, const float* __restrict__ be1,
    float* __restrict__ out)
{
  const int fi = blockIdx.x * 256 + threadIdx.x;
  if (fi >= BN) return;

  // ---- degree 0 ----
  float o0[16];
  #pragma unroll
  for (int o = 0; o < 16; ++o) {
    float a = agg0[(size_t)fi*16 + o];
    #pragma unroll
    for (int i = 0; i < 32; ++i)
      a = fmaf(ws0[o*32+i], h0c[(size_t)fi*32 + i], a);
    o0[o] = a;
  }
  {
    float n0[16], mu = 0.f;
    #pragma unroll
    for (int o = 0; o < 16; ++o) { n0[o] = sqrtf(fmaf(o0[o], o0[o], 1e-12f)); mu += n0[o]; }
    mu *= 0.0625f;
    float var = 0.f;
    #pragma unroll
    for (int o = 0; o < 16; ++o) { float d = n0[o]-mu; var = fmaf(d, d, var); }
    var *= 0.0625f;
    float inv = 1.f / sqrtf(var + 1e-5f);
    #pragma unroll
    for (int o = 0; o < 16; ++o) {
      float t = fmaxf(fmaf((n0[o]-mu)*inv, g0[o], be0[o]), 0.f);
      out[(size_t)fi*16 + o] = t * (o0[o] / n0[o]);
    }
  }

  // ---- degree 1 ----
  float o1[48];
  #pragma unroll
  for (int o = 0; o < 16; ++o) {
    float a0 = agg1[(size_t)fi*48 + o*3+0];
    float a1 = agg1[(size_t)fi*48 + o*3+1];
    float a2 = agg1[(size_t)fi*48 + o*3+2];
    #pragma unroll
    for (int i = 0; i < 32; ++i) {
      float wv = ws1[o*32+i];
      a0 = fmaf(wv, h1c[(size_t)fi*96 + i*3+0], a0);
      a1 = fmaf(wv, h1c[(size_t)fi*96 + i*3+1], a1);
      a2 = fmaf(wv, h1c[(size_t)fi*96 + i*3+2], a2);
    }
    o1[o*3+0] = a0; o1[o*3+1] = a1; o1[o*3+2] = a2;
  }
  {
    float n1[16], mu = 0.f;
    #pragma unroll
    for (int o = 0; o < 16; ++o) {
      float s = fmaf(o1[o*3+0], o1[o*3+0], 1e-12f);
      s = fmaf(o1[o*3+1], o1[o*3+1], s);
      s = fmaf(o1[o*3+2], o1[o*3+2], s);
      n1[o] = sqrtf(s); mu += n1[o];
    }
    mu *= 0.0625f;
    float var = 0.f;
    #pragma unroll
    for (int o = 0; o < 16; ++o) { float d = n1[o]-mu; var = fmaf(d, d, var); }
    var *= 0.0625f;
    float inv = 1.f / sqrtf(var + 1e-5f);
    float* out1 = out + (size_t)BN*16;
    #pragma unroll
    for (int o = 0; o < 16; ++o) {
      float t = fmaxf(fmaf((n1[o]-mu)*inv, g1[o], be1[o]), 0.f);
      #pragma unroll
      for (int m = 0; m < 3; ++m)
        out1[(size_t)fi*48 + o*3+m] = t * (o1[o*3+m] / n1[o]);
    }
  }
}

// ---------------------------------------------------------------------------
extern "C" void kernel_launch(void* const* d_in, const int* in_sizes, int n_in,
                              void* d_out, int out_size, void* d_ws, size_t ws_size,
                              hipStream_t stream)
{
  (void)in_sizes; (void)n_in; (void)out_size; (void)ws_size;
  const float* h0   = (const float*)d_in[0];
  const float* h1   = (const float*)d_in[1];
  const float* uph0 = (const float*)d_in[2];
  const float* uph1 = (const float*)d_in[3];
  const float* xyz  = (const float*)d_in[4];
  const float* xyzp = (const float*)d_in[5];
  const int*   esrc = (const int*)d_in[6];
  // d_in[7] = edge_dst: structurally e>>3 (dst = repeat(arange(BN), 8)); not needed.
  const float* rr   = (const float*)d_in[8];

  // workspace layout (6 MB total)
  float* wsp  = (float*)d_ws;
  float* h0c  = wsp;                         // BN*32
  float* h1c  = h0c + (size_t)BN*32;         // BN*96
  float* agg0 = h1c + (size_t)BN*96;         // BN*16
  float* agg1 = agg0 + (size_t)BN*16;        // BN*48

  interp_kernel<<<BN/256, 256, 0, stream>>>(h0, h1, uph0, uph1, xyz, xyzp, h0c, h1c);

  MsgParams P;
  P.r = rr; P.src = esrc;
  P.b00 = (const float*)d_in[9];  P.b01 = (const float*)d_in[10];
  P.b10 = (const float*)d_in[11]; P.b11 = (const float*)d_in[12];
  for (int p = 0; p < 4; ++p) {
    P.w1[p]  = (const float*)d_in[13 + p*5];
    P.b1a[p] = (const float*)d_in[14 + p*5];
    P.w2[p]  = (const float*)d_in[15 + p*5];
    P.b2a[p] = (const float*)d_in[16 + p*5];
    P.w3[p]  = (const float*)d_in[17 + p*5];
  }
  P.h0c = h0c; P.h1c = h1c; P.agg0 = agg0; P.agg1 = agg1;
  msg_kernel<<<NE/32, 256, 0, stream>>>(P);

  gnorm_kernel<<<BN/256, 256, 0, stream>>>(agg0, agg1, h0c, h1c,
      (const float*)d_in[33], (const float*)d_in[34],
      (const float*)d_in[35], (const float*)d_in[36],
      (const float*)d_in[37], (const float*)d_in[38],
      (float*)d_out);
}

// Round 2
// 637.628 us; speedup vs baseline: 1.3619x; 1.3619x over previous
//
#include <hip/hip_runtime.h>
#include <math.h>

#define NPP   1024
#define BN    8192     // BS*N
#define NE    65536    // BN*KDEG

// ---------------------------------------------------------------------------
// Kernel 1: three_nn + inverse-d^2 interpolation; builds concatenated features
//   h0c [BN][32]      (ch 0..15 = interp(uph0), ch 16..31 = h0)
//   h1c [BN][32][3]   (ch 0..15 = interp(uph1), ch 16..31 = h1)
// ---------------------------------------------------------------------------
__global__ __launch_bounds__(256) void interp_kernel(
    const float* __restrict__ h0, const float* __restrict__ h1,
    const float* __restrict__ uph0, const float* __restrict__ uph1,
    const float* __restrict__ xyz, const float* __restrict__ xyzp,
    float* __restrict__ h0c, float* __restrict__ h1c)
{
  __shared__ float cxs[NPP], cys[NPP], czs[NPP];
  const int tid = threadIdx.x;
  const int fi  = blockIdx.x * 256 + tid;   // block stays in one batch
  const int b   = fi >> 12;                 // N = 4096
  for (int j = tid; j < NPP; j += 256) {
    cxs[j] = xyzp[(b*NPP + j)*3 + 0];
    cys[j] = xyzp[(b*NPP + j)*3 + 1];
    czs[j] = xyzp[(b*NPP + j)*3 + 2];
  }
  __syncthreads();
  const float px = xyz[fi*3+0], py = xyz[fi*3+1], pz = xyz[fi*3+2];
  float d0 = 3.4e38f, d1 = 3.4e38f, d2 = 3.4e38f;
  int   i0 = 0, i1 = 0, i2 = 0;
  for (int j = 0; j < NPP; ++j) {
    float ax = px - cxs[j], ay = py - cys[j], az = pz - czs[j];
    float dd = ax*ax + ay*ay + az*az;
    if (dd < d0)      { d2=d1; i2=i1; d1=d0; i1=i0; d0=dd; i0=j; }
    else if (dd < d1) { d2=d1; i2=i1; d1=dd; i1=j; }
    else if (dd < d2) { d2=dd; i2=j; }
  }
  float w0, w1v, w2v;
  {
    float s0 = sqrtf(fmaxf(d0, 0.f));
    float s1 = sqrtf(fmaxf(d1, 0.f));
    float s2 = sqrtf(fmaxf(d2, 0.f));
    w0  = 1.f / (fmaxf(s0*s0, 1e-10f) + 1e-8f);
    w1v = 1.f / (fmaxf(s1*s1, 1e-10f) + 1e-8f);
    w2v = 1.f / (fmaxf(s2*s2, 1e-10f) + 1e-8f);
    float wsum = w0 + w1v + w2v;
    w0 /= wsum; w1v /= wsum; w2v /= wsum;
  }
  const float* u0 = uph0 + (size_t)b*NPP*16;
  const float* u1 = uph1 + (size_t)b*NPP*48;
  #pragma unroll
  for (int c = 0; c < 16; ++c) {
    h0c[(size_t)fi*32 + c]      = w0*u0[i0*16+c] + w1v*u0[i1*16+c] + w2v*u0[i2*16+c];
    h0c[(size_t)fi*32 + 16 + c] = h0[(size_t)fi*16 + c];
  }
  #pragma unroll
  for (int q = 0; q < 48; ++q) {
    h1c[(size_t)fi*96 + q]      = w0*u1[i0*48+q] + w1v*u1[i1*48+q] + w2v*u1[i2*48+q];
    h1c[(size_t)fi*96 + 48 + q] = h1[(size_t)fi*48 + q];
  }
}

// ---------------------------------------------------------------------------
// Kernel 1b: repack w3_11 [32][(o*32+i)*3+f] -> w3t[f][ih][k][o][ii] contiguous
// flat idx = (((f*2+ih)*32+k)*16+o)*16+ii, size 3*2*32*16*16 = 147456
// ---------------------------------------------------------------------------
__global__ __launch_bounds__(256) void repack11_kernel(
    const float* __restrict__ w3, float* __restrict__ w3t)
{
  int idx = blockIdx.x * 256 + threadIdx.x;
  if (idx >= 147456) return;
  int ii = idx & 15, o = (idx >> 4) & 15, k = (idx >> 8) & 31;
  int ih = (idx >> 13) & 1, f = idx >> 14;
  w3t[idx] = w3[k*1536 + (o*32 + ih*16 + ii)*3 + f];
}

// ---------------------------------------------------------------------------
// Kernel 2: per-edge radial MLP + CG messages, weight stream via UNIFORM
// (scalar) loads, per-lane state in private LDS columns, no barriers in the
// main loop. Thread = 1 edge; block pair splits the 16 output channels 8/8
// (obase = (blockIdx&1)*8) so all w3 indices are wave-uniform.
// ---------------------------------------------------------------------------
__device__ __forceinline__ void run_mlp(
    float rv, int tid,
    const float* __restrict__ w1, const float* __restrict__ b1,
    const float* __restrict__ w2, const float* __restrict__ b2,
    float* Xl)
{
  float x2[32];
  #pragma unroll
  for (int b = 0; b < 32; ++b) x2[b] = b2[b];
  for (int a = 0; a < 32; ++a) {           // a uniform -> w2 row via s_load
    float xa = fmaxf(fmaf(rv, w1[a], b1[a]), 0.f);
    #pragma unroll
    for (int b = 0; b < 32; ++b) x2[b] = fmaf(xa, w2[a*32 + b], x2[b]);
  }
  #pragma unroll
  for (int b = 0; b < 32; ++b) Xl[b*256 + tid] = fmaxf(x2[b], 0.f);
}

__global__ __launch_bounds__(256, 2) void edge_kernel(
    const float* __restrict__ r,    const int* __restrict__ esrc,
    const float* __restrict__ b00,  const float* __restrict__ b01,
    const float* __restrict__ b10,  const float* __restrict__ b11,
    const float* __restrict__ w1_00, const float* __restrict__ bb1_00,
    const float* __restrict__ w2_00, const float* __restrict__ bb2_00,
    const float* __restrict__ w3_00,
    const float* __restrict__ w1_01, const float* __restrict__ bb1_01,
    const float* __restrict__ w2_01, const float* __restrict__ bb2_01,
    const float* __restrict__ w3_01,
    const float* __restrict__ w1_10, const float* __restrict__ bb1_10,
    const float* __restrict__ w2_10, const float* __restrict__ bb2_10,
    const float* __restrict__ w3_10,
    const float* __restrict__ w1_11, const float* __restrict__ bb1_11,
    const float* __restrict__ w2_11, const float* __restrict__ bb2_11,
    const float* __restrict__ w3t11,
    const float* __restrict__ h0c,  const float* __restrict__ h1c,
    float* __restrict__ agg0, float* __restrict__ agg1)
{
  __shared__ float Xl[32*256];   // per-lane MLP output (dynamic k index -> LDS)
  __shared__ float Ml[32*256];   // per-lane messages: v0..7 = msg0, 8..31 = msg1

  const int tid   = threadIdx.x;
  const int obase = (blockIdx.x & 1) * 8;
  const int e0    = (blockIdx.x >> 1) * 256;
  const int e     = e0 + tid;
  const int sidx  = esrc[e];
  const float rv  = r[e];
  const float* h0s = h0c + (size_t)sidx*32;
  const float* h1s = h1c + (size_t)sidx*96;

  float hs0[32];
  #pragma unroll
  for (int i = 0; i < 32; ++i) hs0[i] = h0s[i];

  // ---------------- path 00: msg0 init ----------------
  run_mlp(rv, tid, w1_00, bb1_00, w2_00, bb2_00, Xl);
  {
    const float bv = b00[e];
    for (int oo = 0; oo < 8; ++oo) {               // oo uniform
      float R[32];
      #pragma unroll
      for (int i = 0; i < 32; ++i) R[i] = 0.f;
      const float* wp = w3_00 + (obase + oo)*32;
      for (int k = 0; k < 32; ++k) {               // k uniform -> s_load rows
        float xk = Xl[k*256 + tid];
        #pragma unroll
        for (int i = 0; i < 32; ++i) R[i] = fmaf(xk, wp[k*512 + i], R[i]);
      }
      float G = 0.f;
      #pragma unroll
      for (int i = 0; i < 32; ++i) G = fmaf(R[i], hs0[i], G);
      Ml[oo*256 + tid] = bv * G;
    }
  }

  // ---------------- path 01: msg1 init ----------------
  run_mlp(rv, tid, w1_01, bb1_01, w2_01, bb2_01, Xl);
  {
    const float bm0 = b01[e*3+0], bm1 = b01[e*3+1], bm2 = b01[e*3+2];
    for (int oo = 0; oo < 8; ++oo) {
      float R[32];
      #pragma unroll
      for (int i = 0; i < 32; ++i) R[i] = 0.f;
      const float* wp = w3_01 + (obase + oo)*32;
      for (int k = 0; k < 32; ++k) {
        float xk = Xl[k*256 + tid];
        #pragma unroll
        for (int i = 0; i < 32; ++i) R[i] = fmaf(xk, wp[k*512 + i], R[i]);
      }
      float G = 0.f;
      #pragma unroll
      for (int i = 0; i < 32; ++i) G = fmaf(R[i], hs0[i], G);
      int base = (8 + oo*3)*256 + tid;
      Ml[base]       = bm0 * G;
      Ml[base + 256] = bm1 * G;
      Ml[base + 512] = bm2 * G;
    }
  }

  // ---------------- path 10: msg0 += ----------------
  {
    const float bm0 = b10[e*3+0], bm1 = b10[e*3+1], bm2 = b10[e*3+2];
    float t10[32];
    #pragma unroll
    for (int i = 0; i < 32; ++i)
      t10[i] = bm0*h1s[i*3+0] + bm1*h1s[i*3+1] + bm2*h1s[i*3+2];
    run_mlp(rv, tid, w1_10, bb1_10, w2_10, bb2_10, Xl);
    for (int oo = 0; oo < 8; ++oo) {
      float R[32];
      #pragma unroll
      for (int i = 0; i < 32; ++i) R[i] = 0.f;
      const float* wp = w3_10 + (obase + oo)*32;
      for (int k = 0; k < 32; ++k) {
        float xk = Xl[k*256 + tid];
        #pragma unroll
        for (int i = 0; i < 32; ++i) R[i] = fmaf(xk, wp[k*512 + i], R[i]);
      }
      float G = 0.f;
      #pragma unroll
      for (int i = 0; i < 32; ++i) G = fmaf(R[i], t10[i], G);
      Ml[oo*256 + tid] += G;
    }
  }

  // ---------------- path 11: msg1 += ----------------
  run_mlp(rv, tid, w1_11, bb1_11, w2_11, bb2_11, Xl);
  for (int f = 0; f < 3; ++f) {
    float bm[9];
    #pragma unroll
    for (int m = 0; m < 3; ++m)
      #pragma unroll
      for (int n = 0; n < 3; ++n)
        bm[m*3+n] = b11[e*27 + (m*3+n)*3 + f];
    for (int ih = 0; ih < 2; ++ih) {
      float tmp[48];                                  // [i16][m3]
      #pragma unroll
      for (int i = 0; i < 16; ++i) {
        float hn0 = h1s[(ih*16+i)*3+0];
        float hn1 = h1s[(ih*16+i)*3+1];
        float hn2 = h1s[(ih*16+i)*3+2];
        #pragma unroll
        for (int m = 0; m < 3; ++m)
          tmp[i*3+m] = bm[m*3+0]*hn0 + bm[m*3+1]*hn1 + bm[m*3+2]*hn2;
      }
      const float* wp = w3t11 + (f*2 + ih)*8192 + obase*16;
      for (int oo = 0; oo < 8; ++oo) {
        float R[16];
        #pragma unroll
        for (int i = 0; i < 16; ++i) R[i] = 0.f;
        const float* wo = wp + oo*16;
        for (int k = 0; k < 32; ++k) {
          float xk = Xl[k*256 + tid];
          #pragma unroll
          for (int i = 0; i < 16; ++i) R[i] = fmaf(xk, wo[k*256 + i], R[i]);
        }
        float a0 = 0.f, a1 = 0.f, a2 = 0.f;
        #pragma unroll
        for (int i = 0; i < 16; ++i) {
          a0 = fmaf(R[i], tmp[i*3+0], a0);
          a1 = fmaf(R[i], tmp[i*3+1], a1);
          a2 = fmaf(R[i], tmp[i*3+2], a2);
        }
        int base = (8 + oo*3)*256 + tid;
        Ml[base]       += a0;
        Ml[base + 256] += a1;
        Ml[base + 512] += a2;
      }
    }
  }

  // ---------------- reduce over the 8 edges of each dst ----------------
  __syncthreads();
  const int g = tid >> 3;          // group (dst) within block: 0..31
  const int j = tid & 7;
  const int d = (e0 >> 3) + g;
  #pragma unroll
  for (int q = 0; q < 4; ++q) {
    int v = j*4 + q;
    float s = 0.f;
    #pragma unroll
    for (int l = 0; l < 8; ++l) s += Ml[v*256 + g*8 + l];
    s *= 0.125f;
    if (v < 8) agg0[(size_t)d*16 + obase + v] = s;
    else       agg1[(size_t)d*48 + obase*3 + (v - 8)] = s;
  }
}

// ---------------------------------------------------------------------------
// Kernel 3: self-interaction + GNormSE3; writes final output.
// ---------------------------------------------------------------------------
__global__ __launch_bounds__(256) void gnorm_kernel(
    const float* __restrict__ agg0, const float* __restrict__ agg1,
    const float* __restrict__ h0c, const float* __restrict__ h1c,
    const float* __restrict__ ws0, const float* __restrict__ ws1,
    const float* __restrict__ g0, const float* __restrict__ be0,
    const float* __restrict__ g1, const float* __restrict__ be1,
    float* __restrict__ out)
{
  const int fi = blockIdx.x * 256 + threadIdx.x;
  if (fi >= BN) return;

  float o0[16];
  #pragma unroll
  for (int o = 0; o < 16; ++o) {
    float a = agg0[(size_t)fi*16 + o];
    #pragma unroll
    for (int i = 0; i < 32; ++i)
      a = fmaf(ws0[o*32+i], h0c[(size_t)fi*32 + i], a);
    o0[o] = a;
  }
  {
    float n0[16], mu = 0.f;
    #pragma unroll
    for (int o = 0; o < 16; ++o) { n0[o] = sqrtf(fmaf(o0[o], o0[o], 1e-12f)); mu += n0[o]; }
    mu *= 0.0625f;
    float var = 0.f;
    #pragma unroll
    for (int o = 0; o < 16; ++o) { float d = n0[o]-mu; var = fmaf(d, d, var); }
    var *= 0.0625f;
    float inv = 1.f / sqrtf(var + 1e-5f);
    #pragma unroll
    for (int o = 0; o < 16; ++o) {
      float t = fmaxf(fmaf((n0[o]-mu)*inv, g0[o], be0[o]), 0.f);
      out[(size_t)fi*16 + o] = t * (o0[o] / n0[o]);
    }
  }

  float o1[48];
  #pragma unroll
  for (int o = 0; o < 16; ++o) {
    float a0 = agg1[(size_t)fi*48 + o*3+0];
    float a1 = agg1[(size_t)fi*48 + o*3+1];
    float a2 = agg1[(size_t)fi*48 + o*3+2];
    #pragma unroll
    for (int i = 0; i < 32; ++i) {
      float wv = ws1[o*32+i];
      a0 = fmaf(wv, h1c[(size_t)fi*96 + i*3+0], a0);
      a1 = fmaf(wv, h1c[(size_t)fi*96 + i*3+1], a1);
      a2 = fmaf(wv, h1c[(size_t)fi*96 + i*3+2], a2);
    }
    o1[o*3+0] = a0; o1[o*3+1] = a1; o1[o*3+2] = a2;
  }
  {
    float n1[16], mu = 0.f;
    #pragma unroll
    for (int o = 0; o < 16; ++o) {
      float s = fmaf(o1[o*3+0], o1[o*3+0], 1e-12f);
      s = fmaf(o1[o*3+1], o1[o*3+1], s);
      s = fmaf(o1[o*3+2], o1[o*3+2], s);
      n1[o] = sqrtf(s); mu += n1[o];
    }
    mu *= 0.0625f;
    float var = 0.f;
    #pragma unroll
    for (int o = 0; o < 16; ++o) { float d = n1[o]-mu; var = fmaf(d, d, var); }
    var *= 0.0625f;
    float inv = 1.f / sqrtf(var + 1e-5f);
    float* out1 = out + (size_t)BN*16;
    #pragma unroll
    for (int o = 0; o < 16; ++o) {
      float t = fmaxf(fmaf((n1[o]-mu)*inv, g1[o], be1[o]), 0.f);
      #pragma unroll
      for (int m = 0; m < 3; ++m)
        out1[(size_t)fi*48 + o*3+m] = t * (o1[o*3+m] / n1[o]);
    }
  }
}

// ---------------------------------------------------------------------------
extern "C" void kernel_launch(void* const* d_in, const int* in_sizes, int n_in,
                              void* d_out, int out_size, void* d_ws, size_t ws_size,
                              hipStream_t stream)
{
  (void)in_sizes; (void)n_in; (void)out_size; (void)ws_size;
  const float* h0   = (const float*)d_in[0];
  const float* h1   = (const float*)d_in[1];
  const float* uph0 = (const float*)d_in[2];
  const float* uph1 = (const float*)d_in[3];
  const float* xyz  = (const float*)d_in[4];
  const float* xyzp = (const float*)d_in[5];
  const int*   esrc = (const int*)d_in[6];
  // d_in[7] = edge_dst: structurally e>>3; not needed.
  const float* rr   = (const float*)d_in[8];

  float* wsp  = (float*)d_ws;
  float* h0c  = wsp;                          // BN*32
  float* h1c  = h0c + (size_t)BN*32;          // BN*96
  float* agg0 = h1c + (size_t)BN*96;          // BN*16
  float* agg1 = agg0 + (size_t)BN*16;         // BN*48
  float* w3t  = agg1 + (size_t)BN*48;         // 147456

  interp_kernel<<<BN/256, 256, 0, stream>>>(h0, h1, uph0, uph1, xyz, xyzp, h0c, h1c);
  repack11_kernel<<<576, 256, 0, stream>>>((const float*)d_in[32], w3t);

  edge_kernel<<<NE/256*2, 256, 0, stream>>>(
      rr, esrc,
      (const float*)d_in[9],  (const float*)d_in[10],
      (const float*)d_in[11], (const float*)d_in[12],
      (const float*)d_in[13], (const float*)d_in[14], (const float*)d_in[15],
      (const float*)d_in[16], (const float*)d_in[17],
      (const float*)d_in[18], (const float*)d_in[19], (const float*)d_in[20],
      (const float*)d_in[21], (const float*)d_in[22],
      (const float*)d_in[23], (const float*)d_in[24], (const float*)d_in[25],
      (const float*)d_in[26], (const float*)d_in[27],
      (const float*)d_in[28], (const float*)d_in[29], (const float*)d_in[30],
      (const float*)d_in[31], w3t,
      h0c, h1c, agg0, agg1);

  gnorm_kernel<<<BN/256, 256, 0, stream>>>(agg0, agg1, h0c, h1c,
      (const float*)d_in[33], (const float*)d_in[34],
      (const float*)d_in[35], (const float*)d_in[36],
      (const float*)d_in[37], (const float*)d_in[38],
      (float*)d_out);
}

// Round 3
// 603.046 us; speedup vs baseline: 1.4400x; 1.0573x over previous
//
#include <hip/hip_runtime.h>
#include <math.h>

#define NPP   1024
#define BN    8192     // BS*N
#define NE    65536    // BN*KDEG

// ---------------------------------------------------------------------------
// Kernel 1: three_nn + inverse-d^2 interpolation; builds concatenated features
//   h0c [BN][32]      (ch 0..15 = interp(uph0), ch 16..31 = h0)
//   h1c [BN][32][3]   (ch 0..15 = interp(uph1), ch 16..31 = h1)
// ---------------------------------------------------------------------------
__global__ __launch_bounds__(256) void interp_kernel(
    const float* __restrict__ h0, const float* __restrict__ h1,
    const float* __restrict__ uph0, const float* __restrict__ uph1,
    const float* __restrict__ xyz, const float* __restrict__ xyzp,
    float* __restrict__ h0c, float* __restrict__ h1c)
{
  __shared__ float cxs[NPP], cys[NPP], czs[NPP];
  const int tid = threadIdx.x;
  const int fi  = blockIdx.x * 256 + tid;   // block stays in one batch
  const int b   = fi >> 12;                 // N = 4096
  for (int j = tid; j < NPP; j += 256) {
    cxs[j] = xyzp[(b*NPP + j)*3 + 0];
    cys[j] = xyzp[(b*NPP + j)*3 + 1];
    czs[j] = xyzp[(b*NPP + j)*3 + 2];
  }
  __syncthreads();
  const float px = xyz[fi*3+0], py = xyz[fi*3+1], pz = xyz[fi*3+2];
  float d0 = 3.4e38f, d1 = 3.4e38f, d2 = 3.4e38f;
  int   i0 = 0, i1 = 0, i2 = 0;
  for (int j = 0; j < NPP; ++j) {
    float ax = px - cxs[j], ay = py - cys[j], az = pz - czs[j];
    float dd = ax*ax + ay*ay + az*az;
    if (dd < d0)      { d2=d1; i2=i1; d1=d0; i1=i0; d0=dd; i0=j; }
    else if (dd < d1) { d2=d1; i2=i1; d1=dd; i1=j; }
    else if (dd < d2) { d2=dd; i2=j; }
  }
  float w0, w1v, w2v;
  {
    float s0 = sqrtf(fmaxf(d0, 0.f));
    float s1 = sqrtf(fmaxf(d1, 0.f));
    float s2 = sqrtf(fmaxf(d2, 0.f));
    w0  = 1.f / (fmaxf(s0*s0, 1e-10f) + 1e-8f);
    w1v = 1.f / (fmaxf(s1*s1, 1e-10f) + 1e-8f);
    w2v = 1.f / (fmaxf(s2*s2, 1e-10f) + 1e-8f);
    float wsum = w0 + w1v + w2v;
    w0 /= wsum; w1v /= wsum; w2v /= wsum;
  }
  const float* u0 = uph0 + (size_t)b*NPP*16;
  const float* u1 = uph1 + (size_t)b*NPP*48;
  #pragma unroll
  for (int c = 0; c < 16; ++c) {
    h0c[(size_t)fi*32 + c]      = w0*u0[i0*16+c] + w1v*u0[i1*16+c] + w2v*u0[i2*16+c];
    h0c[(size_t)fi*32 + 16 + c] = h0[(size_t)fi*16 + c];
  }
  #pragma unroll
  for (int q = 0; q < 48; ++q) {
    h1c[(size_t)fi*96 + q]      = w0*u1[i0*48+q] + w1v*u1[i1*48+q] + w2v*u1[i2*48+q];
    h1c[(size_t)fi*96 + 48 + q] = h1[(size_t)fi*48 + q];
  }
}

// ---------------------------------------------------------------------------
// Kernel 1b: repack weight matrices so each o-slice streams contiguously.
//   f=1 paths:  w3r[(o*32 + k)*32 + i]           = w3[k*512 + o*32 + i]
//   path 11  :  w3t[(((f*4+q)*16+o)*32+k)*8+ii]  = w3[k*1536 + (o*32+q*8+ii)*3 + f]
// sizes: 3 x 16384 + 49152 = 98304 elements
// ---------------------------------------------------------------------------
__global__ __launch_bounds__(256) void repack_kernel(
    const float* __restrict__ w00, const float* __restrict__ w01,
    const float* __restrict__ w10, const float* __restrict__ w11,
    float* __restrict__ r00, float* __restrict__ r01,
    float* __restrict__ r10, float* __restrict__ t11)
{
  int idx = blockIdx.x * 256 + threadIdx.x;
  if (idx < 49152) {
    int a = idx & 16383;
    int i = a & 31, k = (a >> 5) & 31, o = a >> 10;
    float v;
    if (idx < 16384)      v = w00[k*512 + o*32 + i];
    else if (idx < 32768) v = w01[k*512 + o*32 + i];
    else                  v = w10[k*512 + o*32 + i];
    if (idx < 16384)      r00[a] = v;
    else if (idx < 32768) r01[a] = v;
    else                  r10[a] = v;
  } else {
    int a = idx - 49152;             // (((f*4+q)*16+o)*32+k)*8+ii
    if (a < 49152) {
      int ii = a & 7, k = (a >> 3) & 31, o = (a >> 8) & 15, q = (a >> 12) & 3, f = a >> 14;
      t11[a] = w11[k*1536 + (o*32 + q*8 + ii)*3 + f];
    }
  }
}

// ---------------------------------------------------------------------------
// radial MLP, all-register. k index into x2 is always static at use sites.
// ---------------------------------------------------------------------------
__device__ __forceinline__ void run_mlp(float rv,
    const float* __restrict__ w1, const float* __restrict__ b1,
    const float* __restrict__ w2, const float* __restrict__ b2,
    float (&x2)[32])
{
  #pragma unroll
  for (int b = 0; b < 32; ++b) x2[b] = b2[b];
  #pragma unroll 1
  for (int a = 0; a < 32; ++a) {     // a uniform -> w2 row via s_load stream
    float xa = fmaxf(fmaf(rv, w1[a], b1[a]), 0.f);
    #pragma unroll
    for (int b = 0; b < 32; ++b) x2[b] = fmaf(xa, w2[a*32 + b], x2[b]);
  }
  #pragma unroll
  for (int b = 0; b < 32; ++b) x2[b] = fmaxf(x2[b], 0.f);
}

// ---------------------------------------------------------------------------
// Kernel 2: per-edge radial MLP + CG messages. ZERO LDS. One lane = one edge,
// 4 of 16 output channels (obase = (blockIdx&3)*4). Weights stream via s_load
// (all w3 indices wave-uniform); per-dst mean via 8-lane shfl_xor butterfly.
// ---------------------------------------------------------------------------
__global__ __launch_bounds__(256, 4) void edge_kernel(
    const float* __restrict__ r,    const int* __restrict__ esrc,
    const float* __restrict__ b00,  const float* __restrict__ b01,
    const float* __restrict__ b10,  const float* __restrict__ b11,
    const float* __restrict__ w1_00, const float* __restrict__ bb1_00,
    const float* __restrict__ w2_00, const float* __restrict__ bb2_00,
    const float* __restrict__ w1_01, const float* __restrict__ bb1_01,
    const float* __restrict__ w2_01, const float* __restrict__ bb2_01,
    const float* __restrict__ w1_10, const float* __restrict__ bb1_10,
    const float* __restrict__ w2_10, const float* __restrict__ bb2_10,
    const float* __restrict__ w1_11, const float* __restrict__ bb1_11,
    const float* __restrict__ w2_11, const float* __restrict__ bb2_11,
    const float* __restrict__ w3r00, const float* __restrict__ w3r01,
    const float* __restrict__ w3r10, const float* __restrict__ w3t11,
    const float* __restrict__ h0c,  const float* __restrict__ h1c,
    float* __restrict__ agg0, float* __restrict__ agg1)
{
  const int tid   = threadIdx.x;
  const int obase = (blockIdx.x & 3) * 4;
  const int e0    = (blockIdx.x >> 2) * 256;
  const int e     = e0 + tid;
  const int sidx  = esrc[e];
  const float rv  = r[e];
  const float* h1s = h1c + (size_t)sidx * 96;

  float msg0[4], msg1[12];
  float src[32];                      // hs0 for p=0,1; t10 for p=2
  #pragma unroll
  for (int i = 0; i < 32; ++i) src[i] = h0c[(size_t)sidx*32 + i];

  // ------------- three f=1 paths share one code instantiation -------------
  #pragma unroll 1
  for (int p = 0; p < 3; ++p) {
    const float* w1p = p==0 ? w1_00  : (p==1 ? w1_01  : w1_10);
    const float* b1p = p==0 ? bb1_00 : (p==1 ? bb1_01 : bb1_10);
    const float* w2p = p==0 ? w2_00  : (p==1 ? w2_01  : w2_10);
    const float* b2p = p==0 ? bb2_00 : (p==1 ? bb2_01 : bb2_10);
    const float* w3p = p==0 ? w3r00  : (p==1 ? w3r01  : w3r10);

    float bv = 0.f, bm0 = 0.f, bm1 = 0.f, bm2 = 0.f;
    if (p == 0) {
      bv = b00[e];
    } else if (p == 1) {
      bm0 = b01[e*3+0]; bm1 = b01[e*3+1]; bm2 = b01[e*3+2];
    } else {
      float c0 = b10[e*3+0], c1 = b10[e*3+1], c2 = b10[e*3+2];
      #pragma unroll
      for (int i = 0; i < 32; ++i)
        src[i] = c0*h1s[i*3+0] + c1*h1s[i*3+1] + c2*h1s[i*3+2];
    }

    float x2[32];
    run_mlp(rv, w1p, b1p, w2p, b2p, x2);

    #pragma unroll
    for (int oo = 0; oo < 4; ++oo) {
      const float* wp = w3p + (obase + oo) * 1024;   // contiguous [k32][i32]
      float R[32];
      #pragma unroll
      for (int i = 0; i < 32; ++i) R[i] = 0.f;
      #pragma unroll
      for (int k = 0; k < 32; ++k) {
        float xk = x2[k];
        #pragma unroll
        for (int i = 0; i < 32; ++i) R[i] = fmaf(xk, wp[k*32 + i], R[i]);
      }
      float G = 0.f;
      #pragma unroll
      for (int i = 0; i < 32; ++i) G = fmaf(R[i], src[i], G);
      if (p == 0) {
        msg0[oo] = bv * G;
      } else if (p == 1) {
        msg1[oo*3+0] = bm0 * G; msg1[oo*3+1] = bm1 * G; msg1[oo*3+2] = bm2 * G;
      } else {
        msg0[oo] += G;
      }
    }
  }

  // ----------------------------- path 11 ----------------------------------
  {
    float x2[32];
    run_mlp(rv, w1_11, bb1_11, w2_11, bb2_11, x2);
    const float* bbase = b11 + (size_t)e * 27;
    #pragma unroll 1
    for (int f = 0; f < 3; ++f) {
      float bm[9];
      #pragma unroll
      for (int mn = 0; mn < 9; ++mn) bm[mn] = bbase[mn*3 + f];
      #pragma unroll 1
      for (int q = 0; q < 4; ++q) {
        float tq[24];                                 // tmp[i8][m3]
        #pragma unroll
        for (int i = 0; i < 8; ++i) {
          float hn0 = h1s[q*24 + i*3 + 0];
          float hn1 = h1s[q*24 + i*3 + 1];
          float hn2 = h1s[q*24 + i*3 + 2];
          tq[i*3+0] = bm[0]*hn0 + bm[1]*hn1 + bm[2]*hn2;
          tq[i*3+1] = bm[3]*hn0 + bm[4]*hn1 + bm[5]*hn2;
          tq[i*3+2] = bm[6]*hn0 + bm[7]*hn1 + bm[8]*hn2;
        }
        const float* wfq = w3t11 + (size_t)(f*4 + q) * 4096;
        #pragma unroll
        for (int oo = 0; oo < 4; ++oo) {
          const float* wp = wfq + (obase + oo) * 256;  // contiguous [k32][i8]
          float R[8];
          #pragma unroll
          for (int i = 0; i < 8; ++i) R[i] = 0.f;
          #pragma unroll
          for (int k = 0; k < 32; ++k) {
            float xk = x2[k];
            #pragma unroll
            for (int i = 0; i < 8; ++i) R[i] = fmaf(xk, wp[k*8 + i], R[i]);
          }
          float a0 = 0.f, a1 = 0.f, a2 = 0.f;
          #pragma unroll
          for (int i = 0; i < 8; ++i) {
            a0 = fmaf(R[i], tq[i*3+0], a0);
            a1 = fmaf(R[i], tq[i*3+1], a1);
            a2 = fmaf(R[i], tq[i*3+2], a2);
          }
          msg1[oo*3+0] += a0; msg1[oo*3+1] += a1; msg1[oo*3+2] += a2;
        }
      }
    }
  }

  // ---------- per-dst mean: 8-lane butterfly, each lane stores 2 ----------
  const int j  = tid & 7;
  const int g  = tid >> 3;
  const int d  = (e0 >> 3) + g;
  const int v0 = j * 2, v1 = v0 + 1;
  float keep0 = 0.f, keep1 = 0.f;
  #pragma unroll
  for (int v = 0; v < 16; ++v) {
    float s = (v < 4) ? msg0[v] : msg1[v-4];
    s += __shfl_xor(s, 1);
    s += __shfl_xor(s, 2);
    s += __shfl_xor(s, 4);
    keep0 = (v == v0) ? s : keep0;
    keep1 = (v == v1) ? s : keep1;
  }
  keep0 *= 0.125f; keep1 *= 0.125f;
  if (v0 < 4) {
    agg0[(size_t)d*16 + obase + v0] = keep0;
    agg0[(size_t)d*16 + obase + v1] = keep1;
  } else {
    agg1[(size_t)d*48 + obase*3 + (v0 - 4)] = keep0;
    agg1[(size_t)d*48 + obase*3 + (v1 - 4)] = keep1;
  }
}

// ---------------------------------------------------------------------------
// Kernel 3: self-interaction + GNormSE3; writes final output.
// ---------------------------------------------------------------------------
__global__ __launch_bounds__(256) void gnorm_kernel(
    const float* __restrict__ agg0, const float* __restrict__ agg1,
    const float* __restrict__ h0c, const float* __restrict__ h1c,
    const float* __restrict__ ws0, const float* __restrict__ ws1,
    const float* __restrict__ g0, const float* __restrict__ be0,
    const float* __restrict__ g1, const float* __restrict__ be1,
    float* __restrict__ out)
{
  const int fi = blockIdx.x * 256 + threadIdx.x;
  if (fi >= BN) return;

  float o0[16];
  #pragma unroll
  for (int o = 0; o < 16; ++o) {
    float a = agg0[(size_t)fi*16 + o];
    #pragma unroll
    for (int i = 0; i < 32; ++i)
      a = fmaf(ws0[o*32+i], h0c[(size_t)fi*32 + i], a);
    o0[o] = a;
  }
  {
    float n0[16], mu = 0.f;
    #pragma unroll
    for (int o = 0; o < 16; ++o) { n0[o] = sqrtf(fmaf(o0[o], o0[o], 1e-12f)); mu += n0[o]; }
    mu *= 0.0625f;
    float var = 0.f;
    #pragma unroll
    for (int o = 0; o < 16; ++o) { float d = n0[o]-mu; var = fmaf(d, d, var); }
    var *= 0.0625f;
    float inv = 1.f / sqrtf(var + 1e-5f);
    #pragma unroll
    for (int o = 0; o < 16; ++o) {
      float t = fmaxf(fmaf((n0[o]-mu)*inv, g0[o], be0[o]), 0.f);
      out[(size_t)fi*16 + o] = t * (o0[o] / n0[o]);
    }
  }

  float o1[48];
  #pragma unroll
  for (int o = 0; o < 16; ++o) {
    float a0 = agg1[(size_t)fi*48 + o*3+0];
    float a1 = agg1[(size_t)fi*48 + o*3+1];
    float a2 = agg1[(size_t)fi*48 + o*3+2];
    #pragma unroll
    for (int i = 0; i < 32; ++i) {
      float wv = ws1[o*32+i];
      a0 = fmaf(wv, h1c[(size_t)fi*96 + i*3+0], a0);
      a1 = fmaf(wv, h1c[(size_t)fi*96 + i*3+1], a1);
      a2 = fmaf(wv, h1c[(size_t)fi*96 + i*3+2], a2);
    }
    o1[o*3+0] = a0; o1[o*3+1] = a1; o1[o*3+2] = a2;
  }
  {
    float n1[16], mu = 0.f;
    #pragma unroll
    for (int o = 0; o < 16; ++o) {
      float s = fmaf(o1[o*3+0], o1[o*3+0], 1e-12f);
      s = fmaf(o1[o*3+1], o1[o*3+1], s);
      s = fmaf(o1[o*3+2], o1[o*3+2], s);
      n1[o] = sqrtf(s); mu += n1[o];
    }
    mu *= 0.0625f;
    float var = 0.f;
    #pragma unroll
    for (int o = 0; o < 16; ++o) { float d = n1[o]-mu; var = fmaf(d, d, var); }
    var *= 0.0625f;
    float inv = 1.f / sqrtf(var + 1e-5f);
    float* out1 = out + (size_t)BN*16;
    #pragma unroll
    for (int o = 0; o < 16; ++o) {
      float t = fmaxf(fmaf((n1[o]-mu)*inv, g1[o], be1[o]), 0.f);
      #pragma unroll
      for (int m = 0; m < 3; ++m)
        out1[(size_t)fi*48 + o*3+m] = t * (o1[o*3+m] / n1[o]);
    }
  }
}

// ---------------------------------------------------------------------------
extern "C" void kernel_launch(void* const* d_in, const int* in_sizes, int n_in,
                              void* d_out, int out_size, void* d_ws, size_t ws_size,
                              hipStream_t stream)
{
  (void)in_sizes; (void)n_in; (void)out_size; (void)ws_size;
  const float* h0   = (const float*)d_in[0];
  const float* h1   = (const float*)d_in[1];
  const float* uph0 = (const float*)d_in[2];
  const float* uph1 = (const float*)d_in[3];
  const float* xyz  = (const float*)d_in[4];
  const float* xyzp = (const float*)d_in[5];
  const int*   esrc = (const int*)d_in[6];
  // d_in[7] = edge_dst: structurally e>>3; not needed.
  const float* rr   = (const float*)d_in[8];

  float* wsp  = (float*)d_ws;
  float* h0c  = wsp;                          // BN*32   = 262144
  float* h1c  = h0c + (size_t)BN*32;          // BN*96   = 786432
  float* agg0 = h1c + (size_t)BN*96;          // BN*16   = 131072
  float* agg1 = agg0 + (size_t)BN*16;         // BN*48   = 393216
  float* w3r00 = agg1 + (size_t)BN*48;        // 16384
  float* w3r01 = w3r00 + 16384;               // 16384
  float* w3r10 = w3r01 + 16384;               // 16384
  float* w3t11 = w3r10 + 16384;               // 49152

  interp_kernel<<<BN/256, 256, 0, stream>>>(h0, h1, uph0, uph1, xyz, xyzp, h0c, h1c);
  repack_kernel<<<384, 256, 0, stream>>>(
      (const float*)d_in[17], (const float*)d_in[22],
      (const float*)d_in[27], (const float*)d_in[32],
      w3r00, w3r01, w3r10, w3t11);

  edge_kernel<<<NE/256*4, 256, 0, stream>>>(
      rr, esrc,
      (const float*)d_in[9],  (const float*)d_in[10],
      (const float*)d_in[11], (const float*)d_in[12],
      (const float*)d_in[13], (const float*)d_in[14],
      (const float*)d_in[15], (const float*)d_in[16],
      (const float*)d_in[18], (const float*)d_in[19],
      (const float*)d_in[20], (const float*)d_in[21],
      (const float*)d_in[23], (const float*)d_in[24],
      (const float*)d_in[25], (const float*)d_in[26],
      (const float*)d_in[28], (const float*)d_in[29],
      (const float*)d_in[30], (const float*)d_in[31],
      w3r00, w3r01, w3r10, w3t11,
      h0c, h1c, agg0, agg1);

  gnorm_kernel<<<BN/256, 256, 0, stream>>>(agg0, agg1, h0c, h1c,
      (const float*)d_in[33], (const float*)d_in[34],
      (const float*)d_in[35], (const float*)d_in[36],
      (const float*)d_in[37], (const float*)d_in[38],
      (float*)d_out);
}

// Round 4
// 278.229 us; speedup vs baseline: 3.1212x; 2.1674x over previous
//
#include <hip/hip_runtime.h>
#include <hip/hip_bf16.h>
#include <math.h>

#define NPP   1024
#define BN    8192     // BS*N
#define NE    65536    // BN*KDEG

typedef __attribute__((ext_vector_type(8))) short bf16x8;
typedef __attribute__((ext_vector_type(4))) float f32x4;

__device__ __forceinline__ short f2bf(float f) {
  __hip_bfloat16 h = __float2bfloat16(f);
  return *reinterpret_cast<short*>(&h);
}

// ---------------------------------------------------------------------------
// Kernel 1: three_nn + inverse-d^2 interpolation; builds concatenated features
//   h0c [BN][32], h1c [BN][32][3].  block=64 -> grid 128 (spread over CUs)
// ---------------------------------------------------------------------------
__global__ __launch_bounds__(64) void interp_kernel(
    const float* __restrict__ h0, const float* __restrict__ h1,
    const float* __restrict__ uph0, const float* __restrict__ uph1,
    const float* __restrict__ xyz, const float* __restrict__ xyzp,
    float* __restrict__ h0c, float* __restrict__ h1c)
{
  __shared__ float cxs[NPP], cys[NPP], czs[NPP];
  const int tid = threadIdx.x;
  const int fi  = blockIdx.x * 64 + tid;    // block stays in one batch
  const int b   = fi >> 12;                 // N = 4096
  for (int j = tid; j < NPP; j += 64) {
    cxs[j] = xyzp[(b*NPP + j)*3 + 0];
    cys[j] = xyzp[(b*NPP + j)*3 + 1];
    czs[j] = xyzp[(b*NPP + j)*3 + 2];
  }
  __syncthreads();
  const float px = xyz[fi*3+0], py = xyz[fi*3+1], pz = xyz[fi*3+2];
  float d0 = 3.4e38f, d1 = 3.4e38f, d2 = 3.4e38f;
  int   i0 = 0, i1 = 0, i2 = 0;
  for (int j = 0; j < NPP; ++j) {
    float ax = px - cxs[j], ay = py - cys[j], az = pz - czs[j];
    float dd = ax*ax + ay*ay + az*az;
    if (dd < d0)      { d2=d1; i2=i1; d1=d0; i1=i0; d0=dd; i0=j; }
    else if (dd < d1) { d2=d1; i2=i1; d1=dd; i1=j; }
    else if (dd < d2) { d2=dd; i2=j; }
  }
  float w0, w1v, w2v;
  {
    float s0 = sqrtf(fmaxf(d0, 0.f));
    float s1 = sqrtf(fmaxf(d1, 0.f));
    float s2 = sqrtf(fmaxf(d2, 0.f));
    w0  = 1.f / (fmaxf(s0*s0, 1e-10f) + 1e-8f);
    w1v = 1.f / (fmaxf(s1*s1, 1e-10f) + 1e-8f);
    w2v = 1.f / (fmaxf(s2*s2, 1e-10f) + 1e-8f);
    float wsum = w0 + w1v + w2v;
    w0 /= wsum; w1v /= wsum; w2v /= wsum;
  }
  const float* u0 = uph0 + (size_t)b*NPP*16;
  const float* u1 = uph1 + (size_t)b*NPP*48;
  #pragma unroll
  for (int c = 0; c < 16; ++c) {
    h0c[(size_t)fi*32 + c]      = w0*u0[i0*16+c] + w1v*u0[i1*16+c] + w2v*u0[i2*16+c];
    h0c[(size_t)fi*32 + 16 + c] = h0[(size_t)fi*16 + c];
  }
  #pragma unroll
  for (int q = 0; q < 48; ++q) {
    h1c[(size_t)fi*96 + q]      = w0*u1[i0*48+q] + w1v*u1[i1*48+q] + w2v*u1[i2*48+q];
    h1c[(size_t)fi*96 + 48 + q] = h1[(size_t)fi*48 + q];
  }
}

// ---------------------------------------------------------------------------
// Kernel 1b: repack w3 to bf16 B-matrices.
//   f=1 paths: Bp[(k*16+o)*32+i] = w3[k*512 + o*32 + i]          (16384 each)
//   path 11 :  B11[((f*32+k)*16+o)*32+i] = w3[k*1536+(o*32+i)*3+f] (49152)
// ---------------------------------------------------------------------------
__global__ __launch_bounds__(256) void repack_bf16(
    const float* __restrict__ w00, const float* __restrict__ w01,
    const float* __restrict__ w10, const float* __restrict__ w11,
    unsigned short* __restrict__ B00, unsigned short* __restrict__ B01,
    unsigned short* __restrict__ B10, unsigned short* __restrict__ B11)
{
  int idx = blockIdx.x * 256 + threadIdx.x;
  if (idx < 49152) {
    int a = idx & 16383;
    int i = a & 31, o = (a >> 5) & 15, k = a >> 9;
    int src = k*512 + o*32 + i;
    if (idx < 16384)      B00[a] = (unsigned short)f2bf(w00[src]);
    else if (idx < 32768) B01[a] = (unsigned short)f2bf(w01[src]);
    else                  B10[a] = (unsigned short)f2bf(w10[src]);
  } else {
    int a = idx - 49152;                   // ((f*32+k)*16+o)*32+i
    if (a < 49152) {
      int i = a & 31, o = (a >> 5) & 15, s = a >> 9;
      int f = s >> 5, k = s & 31;
      B11[a] = (unsigned short)f2bf(w11[k*1536 + (o*32+i)*3 + f]);
    }
  }
}

// ---------------------------------------------------------------------------
// Kernel 2: MFMA edge kernel. Wave = 16 edges; lane = (el = lane&15 edge,
// kg = lane>>4). GEMM#1 (sum over i, K=32) on matrix pipe: Z[e,(k,o)] tile by
// tile; GEMM#2 (sum over k) as 4 VALU fma reading x2 from per-wave LDS table.
// Lane-group kg computes path-kg's radial MLP (per-lane weight pointers).
// ---------------------------------------------------------------------------
struct EP {
  const float *r; const int *esrc;
  const float *b00, *b01, *b10, *b11;
  const float *w1_00, *b1_00, *w2_00, *b2_00;
  const float *w1_01, *b1_01, *w2_01, *b2_01;
  const float *w1_10, *b1_10, *w2_10, *b2_10;
  const float *w1_11, *b1_11, *w2_11, *b2_11;
  const unsigned short *B00, *B01, *B10, *B11;
  const float *h0c, *h1c;
  float *agg0, *agg1;
};

__global__ __launch_bounds__(256) void edge_mfma(EP P)
{
  __shared__ float x2L[32*256];   // [t][tid] per-lane MLP outputs (intra-wave use only)

  const int tid  = threadIdx.x;
  const int wid  = tid >> 6;
  const int lane = tid & 63;
  const int el   = lane & 15;
  const int kg   = lane >> 4;
  const int kg4  = kg << 2;
  const int eb   = blockIdx.x * 64 + wid * 16;
  const int e    = eb + el;
  const int isl  = kg * 8;

  const int   sidx = P.esrc[e];
  const float rv   = P.r[e];

  // ---- radial MLP: lane-group kg computes path kg (per-lane weight ptrs) ----
  {
    const float* w1p = kg==0 ? P.w1_00 : kg==1 ? P.w1_01 : kg==2 ? P.w1_10 : P.w1_11;
    const float* b1p = kg==0 ? P.b1_00 : kg==1 ? P.b1_01 : kg==2 ? P.b1_10 : P.b1_11;
    const float* w2p = kg==0 ? P.w2_00 : kg==1 ? P.w2_01 : kg==2 ? P.w2_10 : P.w2_11;
    const float* b2p = kg==0 ? P.b2_00 : kg==1 ? P.b2_01 : kg==2 ? P.b2_10 : P.b2_11;

    float x2f[32];
    #pragma unroll
    for (int b = 0; b < 32; ++b) x2f[b] = b2p[b];
    #pragma unroll 4
    for (int a = 0; a < 32; ++a) {
      float xa = fmaxf(fmaf(rv, w1p[a], b1p[a]), 0.f);
      #pragma unroll
      for (int b = 0; b < 32; ++b) x2f[b] = fmaf(xa, w2p[a*32+b], x2f[b]);
    }
    #pragma unroll
    for (int b = 0; b < 32; ++b) x2L[b*256 + tid] = fmaxf(x2f[b], 0.f);
  }

  // ---- A-side feature slices ----
  f32x4 h0a = *(const f32x4*)(P.h0c + (size_t)sidx*32 + isl);
  f32x4 h0b = *(const f32x4*)(P.h0c + (size_t)sidx*32 + isl + 4);
  float h1sl[24];
  {
    const float* hp = P.h1c + (size_t)sidx*96 + isl*3;
    #pragma unroll
    for (int q = 0; q < 6; ++q) {
      f32x4 v = *(const f32x4*)(hp + q*4);
      h1sl[q*4+0]=v[0]; h1sl[q*4+1]=v[1]; h1sl[q*4+2]=v[2]; h1sl[q*4+3]=v[3];
    }
  }

  const f32x4 zero4 = {0.f, 0.f, 0.f, 0.f};
  bf16x8 a_h0;
  #pragma unroll
  for (int j = 0; j < 4; ++j) { a_h0[j] = f2bf(h0a[j]); a_h0[j+4] = f2bf(h0b[j]); }

  const int xrow = wid*64 + kg4;   // + path*16 + r  -> lane holding x2_path[edge kg4+r]

  // ---------------- P00: msg0 = b00 * (R00 . hs0) ----------------
  f32x4 macc0 = zero4;
  {
    const unsigned short* bb = P.B00 + el*32 + isl;
    #pragma unroll 4
    for (int t = 0; t < 32; ++t) {
      bf16x8 bv = *(const bf16x8*)(bb + t*512);
      f32x4 z = __builtin_amdgcn_mfma_f32_16x16x32_bf16(a_h0, bv, zero4, 0, 0, 0);
      f32x4 xs = *(const f32x4*)&x2L[t*256 + xrow + 0];     // path 0
      macc0[0] = fmaf(xs[0], z[0], macc0[0]);
      macc0[1] = fmaf(xs[1], z[1], macc0[1]);
      macc0[2] = fmaf(xs[2], z[2], macc0[2]);
      macc0[3] = fmaf(xs[3], z[3], macc0[3]);
    }
  }
  { // scale by b00 per C-row edge (e = eb + kg4 + r)
    f32x4 bv = *(const f32x4*)(P.b00 + eb + kg4);
    macc0[0]*=bv[0]; macc0[1]*=bv[1]; macc0[2]*=bv[2]; macc0[3]*=bv[3];
  }

  // ---------------- P10: msg0 += R10 . t10 ----------------
  {
    const float* bp = P.b10 + (size_t)e*3;
    float c0 = bp[0], c1 = bp[1], c2 = bp[2];
    bf16x8 a_t;
    #pragma unroll
    for (int j = 0; j < 8; ++j)
      a_t[j] = f2bf(c0*h1sl[j*3+0] + c1*h1sl[j*3+1] + c2*h1sl[j*3+2]);
    const unsigned short* bb = P.B10 + el*32 + isl;
    #pragma unroll 4
    for (int t = 0; t < 32; ++t) {
      bf16x8 bv = *(const bf16x8*)(bb + t*512);
      f32x4 z = __builtin_amdgcn_mfma_f32_16x16x32_bf16(a_t, bv, zero4, 0, 0, 0);
      f32x4 xs = *(const f32x4*)&x2L[t*256 + xrow + 32];    // path 2
      macc0[0] = fmaf(xs[0], z[0], macc0[0]);
      macc0[1] = fmaf(xs[1], z[1], macc0[1]);
      macc0[2] = fmaf(xs[2], z[2], macc0[2]);
      macc0[3] = fmaf(xs[3], z[3], macc0[3]);
    }
  }
  // store msg0 mean over 8 edges per dst
  {
    float s = macc0[0]+macc0[1]+macc0[2]+macc0[3];
    s += __shfl_xor(s, 16);
    if ((kg & 1) == 0)
      P.agg0[(size_t)((eb >> 3) + (kg >> 1))*16 + el] = s * 0.125f;
  }

  // ---------------- P01: msg1 = b01[m] * (R01 . hs0) ----------------
  f32x4 c01 = zero4;
  {
    const unsigned short* bb = P.B01 + el*32 + isl;
    #pragma unroll 4
    for (int t = 0; t < 32; ++t) {
      bf16x8 bv = *(const bf16x8*)(bb + t*512);
      f32x4 z = __builtin_amdgcn_mfma_f32_16x16x32_bf16(a_h0, bv, zero4, 0, 0, 0);
      f32x4 xs = *(const f32x4*)&x2L[t*256 + xrow + 16];    // path 1
      c01[0] = fmaf(xs[0], z[0], c01[0]);
      c01[1] = fmaf(xs[1], z[1], c01[1]);
      c01[2] = fmaf(xs[2], z[2], c01[2]);
      c01[3] = fmaf(xs[3], z[3], c01[3]);
    }
  }
  f32x4 m1a, m1b, m1c;
  {
    const float* bp = P.b01 + (size_t)(eb + kg4)*3;   // 12 floats: rows kg4..kg4+3
    f32x4 q0 = *(const f32x4*)(bp);
    f32x4 q1 = *(const f32x4*)(bp + 4);
    f32x4 q2 = *(const f32x4*)(bp + 8);
    m1a[0]=c01[0]*q0[0]; m1a[1]=c01[1]*q0[3]; m1a[2]=c01[2]*q1[2]; m1a[3]=c01[3]*q2[1];
    m1b[0]=c01[0]*q0[1]; m1b[1]=c01[1]*q1[0]; m1b[2]=c01[2]*q1[3]; m1b[3]=c01[3]*q2[2];
    m1c[0]=c01[0]*q0[2]; m1c[1]=c01[1]*q1[1]; m1c[2]=c01[2]*q2[0]; m1c[3]=c01[3]*q2[3];
  }

  // ---------------- P11: msg1 += sum_f R11f . tmp_f ----------------
  {
    const float* b11e = P.b11 + (size_t)e*27;
    #pragma unroll 1
    for (int f = 0; f < 3; ++f) {
      float bm[9];
      #pragma unroll
      for (int mn = 0; mn < 9; ++mn) bm[mn] = b11e[mn*3 + f];
      bf16x8 am0, am1, am2;
      #pragma unroll
      for (int j = 0; j < 8; ++j) {
        float hn0 = h1sl[j*3+0], hn1 = h1sl[j*3+1], hn2 = h1sl[j*3+2];
        am0[j] = f2bf(bm[0]*hn0 + bm[1]*hn1 + bm[2]*hn2);
        am1[j] = f2bf(bm[3]*hn0 + bm[4]*hn1 + bm[5]*hn2);
        am2[j] = f2bf(bm[6]*hn0 + bm[7]*hn1 + bm[8]*hn2);
      }
      const unsigned short* bb = P.B11 + (size_t)f*16384 + el*32 + isl;
      #pragma unroll 4
      for (int t = 0; t < 32; ++t) {
        bf16x8 bv = *(const bf16x8*)(bb + t*512);
        f32x4 z0 = __builtin_amdgcn_mfma_f32_16x16x32_bf16(am0, bv, zero4, 0, 0, 0);
        f32x4 z1 = __builtin_amdgcn_mfma_f32_16x16x32_bf16(am1, bv, zero4, 0, 0, 0);
        f32x4 z2 = __builtin_amdgcn_mfma_f32_16x16x32_bf16(am2, bv, zero4, 0, 0, 0);
        f32x4 xs = *(const f32x4*)&x2L[t*256 + xrow + 48];  // path 3
        m1a[0] = fmaf(xs[0], z0[0], m1a[0]);
        m1a[1] = fmaf(xs[1], z0[1], m1a[1]);
        m1a[2] = fmaf(xs[2], z0[2], m1a[2]);
        m1a[3] = fmaf(xs[3], z0[3], m1a[3]);
        m1b[0] = fmaf(xs[0], z1[0], m1b[0]);
        m1b[1] = fmaf(xs[1], z1[1], m1b[1]);
        m1b[2] = fmaf(xs[2], z1[2], m1b[2]);
        m1b[3] = fmaf(xs[3], z1[3], m1b[3]);
        m1c[0] = fmaf(xs[0], z2[0], m1c[0]);
        m1c[1] = fmaf(xs[1], z2[1], m1c[1]);
        m1c[2] = fmaf(xs[2], z2[2], m1c[2]);
        m1c[3] = fmaf(xs[3], z2[3], m1c[3]);
      }
    }
  }

  // store msg1 mean over 8 edges per dst
  {
    float sa = m1a[0]+m1a[1]+m1a[2]+m1a[3]; sa += __shfl_xor(sa, 16);
    float sb = m1b[0]+m1b[1]+m1b[2]+m1b[3]; sb += __shfl_xor(sb, 16);
    float sc = m1c[0]+m1c[1]+m1c[2]+m1c[3]; sc += __shfl_xor(sc, 16);
    if ((kg & 1) == 0) {
      float* p = P.agg1 + (size_t)((eb >> 3) + (kg >> 1))*48 + el*3;
      p[0] = sa * 0.125f; p[1] = sb * 0.125f; p[2] = sc * 0.125f;
    }
  }
}

// ---------------------------------------------------------------------------
// Kernel 3: self-interaction + GNormSE3; writes final output. block=64.
// ---------------------------------------------------------------------------
__global__ __launch_bounds__(64) void gnorm_kernel(
    const float* __restrict__ agg0, const float* __restrict__ agg1,
    const float* __restrict__ h0c, const float* __restrict__ h1c,
    const float* __restrict__ ws0, const float* __restrict__ ws1,
    const float* __restrict__ g0, const float* __restrict__ be0,
    const float* __restrict__ g1, const float* __restrict__ be1,
    float* __restrict__ out)
{
  const int fi = blockIdx.x * 64 + threadIdx.x;
  if (fi >= BN) return;

  float o0[16];
  #pragma unroll
  for (int o = 0; o < 16; ++o) {
    float a = agg0[(size_t)fi*16 + o];
    #pragma unroll
    for (int i = 0; i < 32; ++i)
      a = fmaf(ws0[o*32+i], h0c[(size_t)fi*32 + i], a);
    o0[o] = a;
  }
  {
    float n0[16], mu = 0.f;
    #pragma unroll
    for (int o = 0; o < 16; ++o) { n0[o] = sqrtf(fmaf(o0[o], o0[o], 1e-12f)); mu += n0[o]; }
    mu *= 0.0625f;
    float var = 0.f;
    #pragma unroll
    for (int o = 0; o < 16; ++o) { float d = n0[o]-mu; var = fmaf(d, d, var); }
    var *= 0.0625f;
    float inv = 1.f / sqrtf(var + 1e-5f);
    #pragma unroll
    for (int o = 0; o < 16; ++o) {
      float t = fmaxf(fmaf((n0[o]-mu)*inv, g0[o], be0[o]), 0.f);
      out[(size_t)fi*16 + o] = t * (o0[o] / n0[o]);
    }
  }

  float o1[48];
  #pragma unroll
  for (int o = 0; o < 16; ++o) {
    float a0 = agg1[(size_t)fi*48 + o*3+0];
    float a1 = agg1[(size_t)fi*48 + o*3+1];
    float a2 = agg1[(size_t)fi*48 + o*3+2];
    #pragma unroll
    for (int i = 0; i < 32; ++i) {
      float wv = ws1[o*32+i];
      a0 = fmaf(wv, h1c[(size_t)fi*96 + i*3+0], a0);
      a1 = fmaf(wv, h1c[(size_t)fi*96 + i*3+1], a1);
      a2 = fmaf(wv, h1c[(size_t)fi*96 + i*3+2], a2);
    }
    o1[o*3+0] = a0; o1[o*3+1] = a1; o1[o*3+2] = a2;
  }
  {
    float n1[16], mu = 0.f;
    #pragma unroll
    for (int o = 0; o < 16; ++o) {
      float s = fmaf(o1[o*3+0], o1[o*3+0], 1e-12f);
      s = fmaf(o1[o*3+1], o1[o*3+1], s);
      s = fmaf(o1[o*3+2], o1[o*3+2], s);
      n1[o] = sqrtf(s); mu += n1[o];
    }
    mu *= 0.0625f;
    float var = 0.f;
    #pragma unroll
    for (int o = 0; o < 16; ++o) { float d = n1[o]-mu; var = fmaf(d, d, var); }
    var *= 0.0625f;
    float inv = 1.f / sqrtf(var + 1e-5f);
    float* out1 = out + (size_t)BN*16;
    #pragma unroll
    for (int o = 0; o < 16; ++o) {
      float t = fmaxf(fmaf((n1[o]-mu)*inv, g1[o], be1[o]), 0.f);
      #pragma unroll
      for (int m = 0; m < 3; ++m)
        out1[(size_t)fi*48 + o*3+m] = t * (o1[o*3+m] / n1[o]);
    }
  }
}

// ---------------------------------------------------------------------------
extern "C" void kernel_launch(void* const* d_in, const int* in_sizes, int n_in,
                              void* d_out, int out_size, void* d_ws, size_t ws_size,
                              hipStream_t stream)
{
  (void)in_sizes; (void)n_in; (void)out_size; (void)ws_size;
  const float* h0   = (const float*)d_in[0];
  const float* h1   = (const float*)d_in[1];
  const float* uph0 = (const float*)d_in[2];
  const float* uph1 = (const float*)d_in[3];
  const float* xyz  = (const float*)d_in[4];
  const float* xyzp = (const float*)d_in[5];
  const int*   esrc = (const int*)d_in[6];
  // d_in[7] = edge_dst: structurally e>>3; not needed.
  const float* rr   = (const float*)d_in[8];

  float* wsp  = (float*)d_ws;
  float* h0c  = wsp;                          // BN*32
  float* h1c  = h0c + (size_t)BN*32;          // BN*96
  float* agg0 = h1c + (size_t)BN*96;          // BN*16
  float* agg1 = agg0 + (size_t)BN*16;         // BN*48
  unsigned short* B00 = (unsigned short*)(agg1 + (size_t)BN*48);
  unsigned short* B01 = B00 + 16384;
  unsigned short* B10 = B01 + 16384;
  unsigned short* B11 = B10 + 16384;          // 49152

  interp_kernel<<<BN/64, 64, 0, stream>>>(h0, h1, uph0, uph1, xyz, xyzp, h0c, h1c);
  repack_bf16<<<384, 256, 0, stream>>>(
      (const float*)d_in[17], (const float*)d_in[22],
      (const float*)d_in[27], (const float*)d_in[32],
      B00, B01, B10, B11);

  EP P;
  P.r = rr; P.esrc = esrc;
  P.b00 = (const float*)d_in[9];  P.b01 = (const float*)d_in[10];
  P.b10 = (const float*)d_in[11]; P.b11 = (const float*)d_in[12];
  P.w1_00 = (const float*)d_in[13]; P.b1_00 = (const float*)d_in[14];
  P.w2_00 = (const float*)d_in[15]; P.b2_00 = (const float*)d_in[16];
  P.w1_01 = (const float*)d_in[18]; P.b1_01 = (const float*)d_in[19];
  P.w2_01 = (const float*)d_in[20]; P.b2_01 = (const float*)d_in[21];
  P.w1_10 = (const float*)d_in[23]; P.b1_10 = (const float*)d_in[24];
  P.w2_10 = (const float*)d_in[25]; P.b2_10 = (const float*)d_in[26];
  P.w1_11 = (const float*)d_in[28]; P.b1_11 = (const float*)d_in[29];
  P.w2_11 = (const float*)d_in[30]; P.b2_11 = (const float*)d_in[31];
  P.B00 = B00; P.B01 = B01; P.B10 = B10; P.B11 = B11;
  P.h0c = h0c; P.h1c = h1c; P.agg0 = agg0; P.agg1 = agg1;

  edge_mfma<<<NE/64, 256, 0, stream>>>(P);

  gnorm_kernel<<<BN/64, 64, 0, stream>>>(agg0, agg1, h0c, h1c,
      (const float*)d_in[33], (const float*)d_in[34],
      (const float*)d_in[35], (const float*)d_in[36],
      (const float*)d_in[37], (const float*)d_in[38],
      (float*)d_out);
}

// Round 5
// 148.556 us; speedup vs baseline: 5.8456x; 1.8729x over previous
//
#include <hip/hip_runtime.h>
#include <hip/hip_bf16.h>
#include <math.h>

#define NPP   1024
#define BN    8192     // BS*N
#define NE    65536    // BN*KDEG

typedef __attribute__((ext_vector_type(8))) short bf16x8;
typedef __attribute__((ext_vector_type(4))) float f32x4;

__device__ __forceinline__ short f2bf(float f) {
  __hip_bfloat16 h = __float2bfloat16(f);
  return *reinterpret_cast<short*>(&h);
}

// ---------------------------------------------------------------------------
// Kernel 1: three_nn + interpolation, one WAVE per fine point.
// Lane scans 16 coarse pts (stride 64) keeping top-3 as packed u64 keys
// (floatbits(d)<<32 | idx : sorts by distance, tie-break smaller idx).
// 6-step shfl_xor butterfly merges sorted triples -> global top-3 in all lanes.
// ---------------------------------------------------------------------------
__device__ __forceinline__ unsigned long long pkkey(float d, int j) {
  return ((unsigned long long)__float_as_uint(d) << 32) | (unsigned int)j;
}

__global__ __launch_bounds__(256) void interp_kernel(
    const float* __restrict__ h0, const float* __restrict__ h1,
    const float* __restrict__ uph0, const float* __restrict__ uph1,
    const float* __restrict__ xyz, const float* __restrict__ xyzp,
    float* __restrict__ h0c, float* __restrict__ h1c)
{
  const int tid  = threadIdx.x;
  const int lane = tid & 63;
  const int wid  = tid >> 6;
  const int fi   = blockIdx.x * 4 + wid;    // 4 fine points per block
  const int b    = fi >> 12;                // N = 4096

  const float px = xyz[fi*3+0], py = xyz[fi*3+1], pz = xyz[fi*3+2];

  unsigned long long k0 = ~0ull, k1 = ~0ull, k2 = ~0ull;
  const float* cbase = xyzp + (size_t)b*NPP*3;
  #pragma unroll 4
  for (int j = lane; j < NPP; j += 64) {
    const float* cp = cbase + j*3;
    float ax = px - cp[0], ay = py - cp[1], az = pz - cp[2];
    float dd = fmaf(az, az, fmaf(ay, ay, ax*ax));
    unsigned long long kk = pkkey(dd, j);
    if (kk < k0)      { k2 = k1; k1 = k0; k0 = kk; }
    else if (kk < k1) { k2 = k1; k1 = kk; }
    else if (kk < k2) { k2 = kk; }
  }
  #pragma unroll
  for (int off = 1; off < 64; off <<= 1) {
    unsigned long long b0 = __shfl_xor(k0, off);
    unsigned long long b1 = __shfl_xor(k1, off);
    unsigned long long b2 = __shfl_xor(k2, off);
    unsigned long long c0, c1, c2;
    if (k0 <= b0) {
      c0 = k0;
      if (k1 <= b0) { c1 = k1; c2 = (k2 <= b0) ? k2 : b0; }
      else          { c1 = b0; c2 = (k1 <= b1) ? k1 : b1; }
    } else {
      c0 = b0;
      if (b1 <= k0) { c1 = b1; c2 = (b2 <= k0) ? b2 : k0; }
      else          { c1 = k0; c2 = (b1 <= k1) ? b1 : k1; }
    }
    k0 = c0; k1 = c1; k2 = c2;
  }
  const int i0 = (int)(k0 & 0xffffffffu);
  const int i1 = (int)(k1 & 0xffffffffu);
  const int i2 = (int)(k2 & 0xffffffffu);
  const float dd0 = __uint_as_float((unsigned)(k0 >> 32));
  const float dd1 = __uint_as_float((unsigned)(k1 >> 32));
  const float dd2 = __uint_as_float((unsigned)(k2 >> 32));

  float w0, w1v, w2v;
  {
    float s0 = sqrtf(fmaxf(dd0, 0.f));
    float s1 = sqrtf(fmaxf(dd1, 0.f));
    float s2 = sqrtf(fmaxf(dd2, 0.f));
    w0  = 1.f / (fmaxf(s0*s0, 1e-10f) + 1e-8f);
    w1v = 1.f / (fmaxf(s1*s1, 1e-10f) + 1e-8f);
    w2v = 1.f / (fmaxf(s2*s2, 1e-10f) + 1e-8f);
    float wsum = w0 + w1v + w2v;
    w0 /= wsum; w1v /= wsum; w2v /= wsum;
  }

  const float* u0 = uph0 + (size_t)b*NPP*16;
  const float* u1 = uph1 + (size_t)b*NPP*48;
  if (lane < 16) {
    int c = lane;
    h0c[(size_t)fi*32 + c] = w0*u0[i0*16+c] + w1v*u0[i1*16+c] + w2v*u0[i2*16+c];
    h0c[(size_t)fi*32 + 16 + c] = h0[(size_t)fi*16 + c];
  } else {
    int q = lane - 16;
    h1c[(size_t)fi*96 + q] = w0*u1[i0*48+q] + w1v*u1[i1*48+q] + w2v*u1[i2*48+q];
    h1c[(size_t)fi*96 + 48 + q] = h1[(size_t)fi*48 + q];
  }
}

// ---------------------------------------------------------------------------
// Kernel 1b: repack w3 to bf16 B-matrices.
//   f=1 paths: Bp[(k*16+o)*32+i] = w3[k*512 + o*32 + i]          (16384 each)
//   path 11 :  B11[((f*32+k)*16+o)*32+i] = w3[k*1536+(o*32+i)*3+f] (49152)
// ---------------------------------------------------------------------------
__global__ __launch_bounds__(256) void repack_bf16(
    const float* __restrict__ w00, const float* __restrict__ w01,
    const float* __restrict__ w10, const float* __restrict__ w11,
    unsigned short* __restrict__ B00, unsigned short* __restrict__ B01,
    unsigned short* __restrict__ B10, unsigned short* __restrict__ B11)
{
  int idx = blockIdx.x * 256 + threadIdx.x;
  if (idx < 49152) {
    int a = idx & 16383;
    int i = a & 31, o = (a >> 5) & 15, k = a >> 9;
    int src = k*512 + o*32 + i;
    if (idx < 16384)      B00[a] = (unsigned short)f2bf(w00[src]);
    else if (idx < 32768) B01[a] = (unsigned short)f2bf(w01[src]);
    else                  B10[a] = (unsigned short)f2bf(w10[src]);
  } else {
    int a = idx - 49152;                   // ((f*32+k)*16+o)*32+i
    if (a < 49152) {
      int i = a & 31, o = (a >> 5) & 15, s = a >> 9;
      int f = s >> 5, k = s & 31;
      B11[a] = (unsigned short)f2bf(w11[k*1536 + (o*32+i)*3 + f]);
    }
  }
}

// ---------------------------------------------------------------------------
// Kernel 2: MFMA edge kernel (unchanged from R4). Wave = 16 edges.
// ---------------------------------------------------------------------------
struct EP {
  const float *r; const int *esrc;
  const float *b00, *b01, *b10, *b11;
  const float *w1_00, *b1_00, *w2_00, *b2_00;
  const float *w1_01, *b1_01, *w2_01, *b2_01;
  const float *w1_10, *b1_10, *w2_10, *b2_10;
  const float *w1_11, *b1_11, *w2_11, *b2_11;
  const unsigned short *B00, *B01, *B10, *B11;
  const float *h0c, *h1c;
  float *agg0, *agg1;
};

__global__ __launch_bounds__(256) void edge_mfma(EP P)
{
  __shared__ float x2L[32*256];   // [t][tid] per-lane MLP outputs (intra-wave use only)

  const int tid  = threadIdx.x;
  const int wid  = tid >> 6;
  const int lane = tid & 63;
  const int el   = lane & 15;
  const int kg   = lane >> 4;
  const int kg4  = kg << 2;
  const int eb   = blockIdx.x * 64 + wid * 16;
  const int e    = eb + el;
  const int isl  = kg * 8;

  const int   sidx = P.esrc[e];
  const float rv   = P.r[e];

  // ---- radial MLP: lane-group kg computes path kg (per-lane weight ptrs) ----
  {
    const float* w1p = kg==0 ? P.w1_00 : kg==1 ? P.w1_01 : kg==2 ? P.w1_10 : P.w1_11;
    const float* b1p = kg==0 ? P.b1_00 : kg==1 ? P.b1_01 : kg==2 ? P.b1_10 : P.b1_11;
    const float* w2p = kg==0 ? P.w2_00 : kg==1 ? P.w2_01 : kg==2 ? P.w2_10 : P.w2_11;
    const float* b2p = kg==0 ? P.b2_00 : kg==1 ? P.b2_01 : kg==2 ? P.b2_10 : P.b2_11;

    float x2f[32];
    #pragma unroll
    for (int b = 0; b < 32; ++b) x2f[b] = b2p[b];
    #pragma unroll 4
    for (int a = 0; a < 32; ++a) {
      float xa = fmaxf(fmaf(rv, w1p[a], b1p[a]), 0.f);
      #pragma unroll
      for (int b = 0; b < 32; ++b) x2f[b] = fmaf(xa, w2p[a*32+b], x2f[b]);
    }
    #pragma unroll
    for (int b = 0; b < 32; ++b) x2L[b*256 + tid] = fmaxf(x2f[b], 0.f);
  }

  // ---- A-side feature slices ----
  f32x4 h0a = *(const f32x4*)(P.h0c + (size_t)sidx*32 + isl);
  f32x4 h0b = *(const f32x4*)(P.h0c + (size_t)sidx*32 + isl + 4);
  float h1sl[24];
  {
    const float* hp = P.h1c + (size_t)sidx*96 + isl*3;
    #pragma unroll
    for (int q = 0; q < 6; ++q) {
      f32x4 v = *(const f32x4*)(hp + q*4);
      h1sl[q*4+0]=v[0]; h1sl[q*4+1]=v[1]; h1sl[q*4+2]=v[2]; h1sl[q*4+3]=v[3];
    }
  }

  const f32x4 zero4 = {0.f, 0.f, 0.f, 0.f};
  bf16x8 a_h0;
  #pragma unroll
  for (int j = 0; j < 4; ++j) { a_h0[j] = f2bf(h0a[j]); a_h0[j+4] = f2bf(h0b[j]); }

  const int xrow = wid*64 + kg4;   // + path*16 + r  -> lane holding x2_path[edge kg4+r]

  // ---------------- P00: msg0 = b00 * (R00 . hs0) ----------------
  f32x4 macc0 = zero4;
  {
    const unsigned short* bb = P.B00 + el*32 + isl;
    #pragma unroll 4
    for (int t = 0; t < 32; ++t) {
      bf16x8 bv = *(const bf16x8*)(bb + t*512);
      f32x4 z = __builtin_amdgcn_mfma_f32_16x16x32_bf16(a_h0, bv, zero4, 0, 0, 0);
      f32x4 xs = *(const f32x4*)&x2L[t*256 + xrow + 0];     // path 0
      macc0[0] = fmaf(xs[0], z[0], macc0[0]);
      macc0[1] = fmaf(xs[1], z[1], macc0[1]);
      macc0[2] = fmaf(xs[2], z[2], macc0[2]);
      macc0[3] = fmaf(xs[3], z[3], macc0[3]);
    }
  }
  { // scale by b00 per C-row edge (e = eb + kg4 + r)
    f32x4 bv = *(const f32x4*)(P.b00 + eb + kg4);
    macc0[0]*=bv[0]; macc0[1]*=bv[1]; macc0[2]*=bv[2]; macc0[3]*=bv[3];
  }

  // ---------------- P10: msg0 += R10 . t10 ----------------
  {
    const float* bp = P.b10 + (size_t)e*3;
    float c0 = bp[0], c1 = bp[1], c2 = bp[2];
    bf16x8 a_t;
    #pragma unroll
    for (int j = 0; j < 8; ++j)
      a_t[j] = f2bf(c0*h1sl[j*3+0] + c1*h1sl[j*3+1] + c2*h1sl[j*3+2]);
    const unsigned short* bb = P.B10 + el*32 + isl;
    #pragma unroll 4
    for (int t = 0; t < 32; ++t) {
      bf16x8 bv = *(const bf16x8*)(bb + t*512);
      f32x4 z = __builtin_amdgcn_mfma_f32_16x16x32_bf16(a_t, bv, zero4, 0, 0, 0);
      f32x4 xs = *(const f32x4*)&x2L[t*256 + xrow + 32];    // path 2
      macc0[0] = fmaf(xs[0], z[0], macc0[0]);
      macc0[1] = fmaf(xs[1], z[1], macc0[1]);
      macc0[2] = fmaf(xs[2], z[2], macc0[2]);
      macc0[3] = fmaf(xs[3], z[3], macc0[3]);
    }
  }
  // store msg0 mean over 8 edges per dst
  {
    float s = macc0[0]+macc0[1]+macc0[2]+macc0[3];
    s += __shfl_xor(s, 16);
    if ((kg & 1) == 0)
      P.agg0[(size_t)((eb >> 3) + (kg >> 1))*16 + el] = s * 0.125f;
  }

  // ---------------- P01: msg1 = b01[m] * (R01 . hs0) ----------------
  f32x4 c01 = zero4;
  {
    const unsigned short* bb = P.B01 + el*32 + isl;
    #pragma unroll 4
    for (int t = 0; t < 32; ++t) {
      bf16x8 bv = *(const bf16x8*)(bb + t*512);
      f32x4 z = __builtin_amdgcn_mfma_f32_16x16x32_bf16(a_h0, bv, zero4, 0, 0, 0);
      f32x4 xs = *(const f32x4*)&x2L[t*256 + xrow + 16];    // path 1
      c01[0] = fmaf(xs[0], z[0], c01[0]);
      c01[1] = fmaf(xs[1], z[1], c01[1]);
      c01[2] = fmaf(xs[2], z[2], c01[2]);
      c01[3] = fmaf(xs[3], z[3], c01[3]);
    }
  }
  f32x4 m1a, m1b, m1c;
  {
    const float* bp = P.b01 + (size_t)(eb + kg4)*3;   // 12 floats: rows kg4..kg4+3
    f32x4 q0 = *(const f32x4*)(bp);
    f32x4 q1 = *(const f32x4*)(bp + 4);
    f32x4 q2 = *(const f32x4*)(bp + 8);
    m1a[0]=c01[0]*q0[0]; m1a[1]=c01[1]*q0[3]; m1a[2]=c01[2]*q1[2]; m1a[3]=c01[3]*q2[1];
    m1b[0]=c01[0]*q0[1]; m1b[1]=c01[1]*q1[0]; m1b[2]=c01[2]*q1[3]; m1b[3]=c01[3]*q2[2];
    m1c[0]=c01[0]*q0[2]; m1c[1]=c01[1]*q1[1]; m1c[2]=c01[2]*q2[0]; m1c[3]=c01[3]*q2[3];
  }

  // ---------------- P11: msg1 += sum_f R11f . tmp_f ----------------
  {
    const float* b11e = P.b11 + (size_t)e*27;
    #pragma unroll 1
    for (int f = 0; f < 3; ++f) {
      float bm[9];
      #pragma unroll
      for (int mn = 0; mn < 9; ++mn) bm[mn] = b11e[mn*3 + f];
      bf16x8 am0, am1, am2;
      #pragma unroll
      for (int j = 0; j < 8; ++j) {
        float hn0 = h1sl[j*3+0], hn1 = h1sl[j*3+1], hn2 = h1sl[j*3+2];
        am0[j] = f2bf(bm[0]*hn0 + bm[1]*hn1 + bm[2]*hn2);
        am1[j] = f2bf(bm[3]*hn0 + bm[4]*hn1 + bm[5]*hn2);
        am2[j] = f2bf(bm[6]*hn0 + bm[7]*hn1 + bm[8]*hn2);
      }
      const unsigned short* bb = P.B11 + (size_t)f*16384 + el*32 + isl;
      #pragma unroll 4
      for (int t = 0; t < 32; ++t) {
        bf16x8 bv = *(const bf16x8*)(bb + t*512);
        f32x4 z0 = __builtin_amdgcn_mfma_f32_16x16x32_bf16(am0, bv, zero4, 0, 0, 0);
        f32x4 z1 = __builtin_amdgcn_mfma_f32_16x16x32_bf16(am1, bv, zero4, 0, 0, 0);
        f32x4 z2 = __builtin_amdgcn_mfma_f32_16x16x32_bf16(am2, bv, zero4, 0, 0, 0);
        f32x4 xs = *(const f32x4*)&x2L[t*256 + xrow + 48];  // path 3
        m1a[0] = fmaf(xs[0], z0[0], m1a[0]);
        m1a[1] = fmaf(xs[1], z0[1], m1a[1]);
        m1a[2] = fmaf(xs[2], z0[2], m1a[2]);
        m1a[3] = fmaf(xs[3], z0[3], m1a[3]);
        m1b[0] = fmaf(xs[0], z1[0], m1b[0]);
        m1b[1] = fmaf(xs[1], z1[1], m1b[1]);
        m1b[2] = fmaf(xs[2], z1[2], m1b[2]);
        m1b[3] = fmaf(xs[3], z1[3], m1b[3]);
        m1c[0] = fmaf(xs[0], z2[0], m1c[0]);
        m1c[1] = fmaf(xs[1], z2[1], m1c[1]);
        m1c[2] = fmaf(xs[2], z2[2], m1c[2]);
        m1c[3] = fmaf(xs[3], z2[3], m1c[3]);
      }
    }
  }

  // store msg1 mean over 8 edges per dst
  {
    float sa = m1a[0]+m1a[1]+m1a[2]+m1a[3]; sa += __shfl_xor(sa, 16);
    float sb = m1b[0]+m1b[1]+m1b[2]+m1b[3]; sb += __shfl_xor(sb, 16);
    float sc = m1c[0]+m1c[1]+m1c[2]+m1c[3]; sc += __shfl_xor(sc, 16);
    if ((kg & 1) == 0) {
      float* p = P.agg1 + (size_t)((eb >> 3) + (kg >> 1))*48 + el*3;
      p[0] = sa * 0.125f; p[1] = sb * 0.125f; p[2] = sc * 0.125f;
    }
  }
}

// ---------------------------------------------------------------------------
// Kernel 3: self-interaction + GNormSE3, 4 lanes per node (aligned 4-lane
// groups; mu/var via shfl_xor(1,2)). 32768 threads, grid 128.
// ---------------------------------------------------------------------------
__global__ __launch_bounds__(256) void gnorm_kernel(
    const float* __restrict__ agg0, const float* __restrict__ agg1,
    const float* __restrict__ h0c, const float* __restrict__ h1c,
    const float* __restrict__ ws0, const float* __restrict__ ws1,
    const float* __restrict__ g0, const float* __restrict__ be0,
    const float* __restrict__ g1, const float* __restrict__ be1,
    float* __restrict__ out)
{
  const int gt  = blockIdx.x * 256 + threadIdx.x;
  const int fi  = gt >> 2;
  const int t4  = gt & 3;          // this lane's channel quarter: o = t4*4..t4*4+3
  const int ob  = t4 * 4;

  const float* h0p = h0c + (size_t)fi*32;
  const float* h1p = h1c + (size_t)fi*96;

  // ---- degree 0 ----
  float o0[4];
  #pragma unroll
  for (int oo = 0; oo < 4; ++oo) {
    int o = ob + oo;
    float a = agg0[(size_t)fi*16 + o];
    #pragma unroll
    for (int i = 0; i < 32; ++i)
      a = fmaf(ws0[o*32+i], h0p[i], a);
    o0[oo] = a;
  }
  {
    float n0[4], lmu = 0.f;
    #pragma unroll
    for (int oo = 0; oo < 4; ++oo) { n0[oo] = sqrtf(fmaf(o0[oo], o0[oo], 1e-12f)); lmu += n0[oo]; }
    lmu += __shfl_xor(lmu, 1); lmu += __shfl_xor(lmu, 2);
    float mu = lmu * 0.0625f;
    float lv = 0.f;
    #pragma unroll
    for (int oo = 0; oo < 4; ++oo) { float d = n0[oo]-mu; lv = fmaf(d, d, lv); }
    lv += __shfl_xor(lv, 1); lv += __shfl_xor(lv, 2);
    float inv = 1.f / sqrtf(lv * 0.0625f + 1e-5f);
    #pragma unroll
    for (int oo = 0; oo < 4; ++oo) {
      int o = ob + oo;
      float t = fmaxf(fmaf((n0[oo]-mu)*inv, g0[o], be0[o]), 0.f);
      out[(size_t)fi*16 + o] = t * (o0[oo] / n0[oo]);
    }
  }

  // ---- degree 1 ----
  float o1[12];
  #pragma unroll
  for (int oo = 0; oo < 4; ++oo) {
    int o = ob + oo;
    float a0 = agg1[(size_t)fi*48 + o*3+0];
    float a1 = agg1[(size_t)fi*48 + o*3+1];
    float a2 = agg1[(size_t)fi*48 + o*3+2];
    #pragma unroll
    for (int i = 0; i < 32; ++i) {
      float wv = ws1[o*32+i];
      a0 = fmaf(wv, h1p[i*3+0], a0);
      a1 = fmaf(wv, h1p[i*3+1], a1);
      a2 = fmaf(wv, h1p[i*3+2], a2);
    }
    o1[oo*3+0] = a0; o1[oo*3+1] = a1; o1[oo*3+2] = a2;
  }
  {
    float n1[4], lmu = 0.f;
    #pragma unroll
    for (int oo = 0; oo < 4; ++oo) {
      float s = fmaf(o1[oo*3+0], o1[oo*3+0], 1e-12f);
      s = fmaf(o1[oo*3+1], o1[oo*3+1], s);
      s = fmaf(o1[oo*3+2], o1[oo*3+2], s);
      n1[oo] = sqrtf(s); lmu += n1[oo];
    }
    lmu += __shfl_xor(lmu, 1); lmu += __shfl_xor(lmu, 2);
    float mu = lmu * 0.0625f;
    float lv = 0.f;
    #pragma unroll
    for (int oo = 0; oo < 4; ++oo) { float d = n1[oo]-mu; lv = fmaf(d, d, lv); }
    lv += __shfl_xor(lv, 1); lv += __shfl_xor(lv, 2);
    float inv = 1.f / sqrtf(lv * 0.0625f + 1e-5f);
    float* out1 = out + (size_t)BN*16;
    #pragma unroll
    for (int oo = 0; oo < 4; ++oo) {
      int o = ob + oo;
      float t = fmaxf(fmaf((n1[oo]-mu)*inv, g1[o], be1[o]), 0.f);
      #pragma unroll
      for (int m = 0; m < 3; ++m)
        out1[(size_t)fi*48 + o*3+m] = t * (o1[oo*3+m] / n1[oo]);
    }
  }
}

// ---------------------------------------------------------------------------
extern "C" void kernel_launch(void* const* d_in, const int* in_sizes, int n_in,
                              void* d_out, int out_size, void* d_ws, size_t ws_size,
                              hipStream_t stream)
{
  (void)in_sizes; (void)n_in; (void)out_size; (void)ws_size;
  const float* h0   = (const float*)d_in[0];
  const float* h1   = (const float*)d_in[1];
  const float* uph0 = (const float*)d_in[2];
  const float* uph1 = (const float*)d_in[3];
  const float* xyz  = (const float*)d_in[4];
  const float* xyzp = (const float*)d_in[5];
  const int*   esrc = (const int*)d_in[6];
  // d_in[7] = edge_dst: structurally e>>3; not needed.
  const float* rr   = (const float*)d_in[8];

  float* wsp  = (float*)d_ws;
  float* h0c  = wsp;                          // BN*32
  float* h1c  = h0c + (size_t)BN*32;          // BN*96
  float* agg0 = h1c + (size_t)BN*96;          // BN*16
  float* agg1 = agg0 + (size_t)BN*16;         // BN*48
  unsigned short* B00 = (unsigned short*)(agg1 + (size_t)BN*48);
  unsigned short* B01 = B00 + 16384;
  unsigned short* B10 = B01 + 16384;
  unsigned short* B11 = B10 + 16384;          // 49152

  interp_kernel<<<BN/4, 256, 0, stream>>>(h0, h1, uph0, uph1, xyz, xyzp, h0c, h1c);
  repack_bf16<<<384, 256, 0, stream>>>(
      (const float*)d_in[17], (const float*)d_in[22],
      (const float*)d_in[27], (const float*)d_in[32],
      B00, B01, B10, B11);

  EP P;
  P.r = rr; P.esrc = esrc;
  P.b00 = (const float*)d_in[9];  P.b01 = (const float*)d_in[10];
  P.b10 = (const float*)d_in[11]; P.b11 = (const float*)d_in[12];
  P.w1_00 = (const float*)d_in[13]; P.b1_00 = (const float*)d_in[14];
  P.w2_00 = (const float*)d_in[15]; P.b2_00 = (const float*)d_in[16];
  P.w1_01 = (const float*)d_in[18]; P.b1_01 = (const float*)d_in[19];
  P.w2_01 = (const float*)d_in[20]; P.b2_01 = (const float*)d_in[21];
  P.w1_10 = (const float*)d_in[23]; P.b1_10 = (const float*)d_in[24];
  P.w2_10 = (const float*)d_in[25]; P.b2_10 = (const float*)d_in[26];
  P.w1_11 = (const float*)d_in[28]; P.b1_11 = (const float*)d_in[29];
  P.w2_11 = (const float*)d_in[30]; P.b2_11 = (const float*)d_in[31];
  P.B00 = B00; P.B01 = B01; P.B10 = B10; P.B11 = B11;
  P.h0c = h0c; P.h1c = h1c; P.agg0 = agg0; P.agg1 = agg1;

  edge_mfma<<<NE/64, 256, 0, stream>>>(P);

  gnorm_kernel<<<BN*4/256, 256, 0, stream>>>(agg0, agg1, h0c, h1c,
      (const float*)d_in[33], (const float*)d_in[34],
      (const float*)d_in[35], (const float*)d_in[36],
      (const float*)d_in[37], (const float*)d_in[38],
      (float*)d_out);
}

// Round 8
// 105.004 us; speedup vs baseline: 8.2702x; 1.4148x over previous
//
#include <hip/hip_runtime.h>
#include <hip/hip_bf16.h>
#include <math.h>

#define NPP   1024
#define BN    8192     // BS*N
#define NE    65536    // BN*KDEG

typedef __attribute__((ext_vector_type(8))) short bf16x8;
typedef __attribute__((ext_vector_type(4))) float f32x4;

__device__ __forceinline__ short f2bf(float f) {
  __hip_bfloat16 h = __float2bfloat16(f);
  return *reinterpret_cast<short*>(&h);
}
__device__ __forceinline__ float b2f(short h) {
  unsigned u = ((unsigned)(unsigned short)h) << 16;
  return __uint_as_float(u);
}

// ---------------------------------------------------------------------------
// Kernel 1: three_nn + interpolation, one WAVE per fine point (R5, passing).
// ---------------------------------------------------------------------------
__device__ __forceinline__ unsigned long long pkkey(float d, int j) {
  return ((unsigned long long)__float_as_uint(d) << 32) | (unsigned int)j;
}

__global__ __launch_bounds__(256) void interp_kernel(
    const float* __restrict__ h0, const float* __restrict__ h1,
    const float* __restrict__ uph0, const float* __restrict__ uph1,
    const float* __restrict__ xyz, const float* __restrict__ xyzp,
    float* __restrict__ h0c, float* __restrict__ h1c)
{
  const int tid  = threadIdx.x;
  const int lane = tid & 63;
  const int wid  = tid >> 6;
  const int fi   = blockIdx.x * 4 + wid;
  const int b    = fi >> 12;

  const float px = xyz[fi*3+0], py = xyz[fi*3+1], pz = xyz[fi*3+2];

  unsigned long long k0 = ~0ull, k1 = ~0ull, k2 = ~0ull;
  const float* cbase = xyzp + (size_t)b*NPP*3;
  #pragma unroll 4
  for (int j = lane; j < NPP; j += 64) {
    const float* cp = cbase + j*3;
    float ax = px - cp[0], ay = py - cp[1], az = pz - cp[2];
    float dd = fmaf(az, az, fmaf(ay, ay, ax*ax));
    unsigned long long kk = pkkey(dd, j);
    if (kk < k0)      { k2 = k1; k1 = k0; k0 = kk; }
    else if (kk < k1) { k2 = k1; k1 = kk; }
    else if (kk < k2) { k2 = kk; }
  }
  #pragma unroll
  for (int off = 1; off < 64; off <<= 1) {
    unsigned long long b0 = __shfl_xor(k0, off);
    unsigned long long b1 = __shfl_xor(k1, off);
    unsigned long long b2 = __shfl_xor(k2, off);
    unsigned long long c0, c1, c2;
    if (k0 <= b0) {
      c0 = k0;
      if (k1 <= b0) { c1 = k1; c2 = (k2 <= b0) ? k2 : b0; }
      else          { c1 = b0; c2 = (k1 <= b1) ? k1 : b1; }
    } else {
      c0 = b0;
      if (b1 <= k0) { c1 = b1; c2 = (b2 <= k0) ? b2 : k0; }
      else          { c1 = k0; c2 = (b1 <= k1) ? b1 : k1; }
    }
    k0 = c0; k1 = c1; k2 = c2;
  }
  const int i0 = (int)(k0 & 0xffffffffu);
  const int i1 = (int)(k1 & 0xffffffffu);
  const int i2 = (int)(k2 & 0xffffffffu);
  const float dd0 = __uint_as_float((unsigned)(k0 >> 32));
  const float dd1 = __uint_as_float((unsigned)(k1 >> 32));
  const float dd2 = __uint_as_float((unsigned)(k2 >> 32));

  float w0, w1v, w2v;
  {
    float s0 = sqrtf(fmaxf(dd0, 0.f));
    float s1 = sqrtf(fmaxf(dd1, 0.f));
    float s2 = sqrtf(fmaxf(dd2, 0.f));
    w0  = 1.f / (fmaxf(s0*s0, 1e-10f) + 1e-8f);
    w1v = 1.f / (fmaxf(s1*s1, 1e-10f) + 1e-8f);
    w2v = 1.f / (fmaxf(s2*s2, 1e-10f) + 1e-8f);
    float wsum = w0 + w1v + w2v;
    w0 /= wsum; w1v /= wsum; w2v /= wsum;
  }

  const float* u0 = uph0 + (size_t)b*NPP*16;
  const float* u1 = uph1 + (size_t)b*NPP*48;
  if (lane < 16) {
    int c = lane;
    h0c[(size_t)fi*32 + c] = w0*u0[i0*16+c] + w1v*u0[i1*16+c] + w2v*u0[i2*16+c];
    h0c[(size_t)fi*32 + 16 + c] = h0[(size_t)fi*16 + c];
  } else {
    int q = lane - 16;
    h1c[(size_t)fi*96 + q] = w0*u1[i0*48+q] + w1v*u1[i1*48+q] + w2v*u1[i2*48+q];
    h1c[(size_t)fi*96 + 48 + q] = h1[(size_t)fi*48 + q];
  }
}

// ---------------------------------------------------------------------------
// Kernel 1b: repack to bf16 (R5 layouts + W2 hi/lo planes).
//  B00/B01/B10: [(t*16+o)*32+i] = w3[t*512 + o*32 + i]            (16384 each)
//  B11: [((f*32+t)*16+o)*32+i]  = w3_11[t*1536 + (o*32+i)*3 + f]  (49152)
//  W2H/W2L: [p][b*32+a]         = hi/lo bf16 split of w2_p[a*32+b] (4096 each)
// ---------------------------------------------------------------------------
__global__ __launch_bounds__(256) void repack_bf16(
    const float* __restrict__ w00, const float* __restrict__ w01,
    const float* __restrict__ w10, const float* __restrict__ w11,
    const float* __restrict__ w2_00, const float* __restrict__ w2_01,
    const float* __restrict__ w2_10, const float* __restrict__ w2_11,
    unsigned short* __restrict__ B00, unsigned short* __restrict__ B01,
    unsigned short* __restrict__ B10, unsigned short* __restrict__ B11,
    unsigned short* __restrict__ W2H, unsigned short* __restrict__ W2L)
{
  int idx = blockIdx.x * 256 + threadIdx.x;
  if (idx < 49152) {
    int a = idx & 16383;
    int i = a & 31, o = (a >> 5) & 15, k = a >> 9;
    int src = k*512 + o*32 + i;
    if (idx < 16384)      B00[a] = (unsigned short)f2bf(w00[src]);
    else if (idx < 32768) B01[a] = (unsigned short)f2bf(w01[src]);
    else                  B10[a] = (unsigned short)f2bf(w10[src]);
  } else if (idx < 98304) {
    int a = idx - 49152;                   // ((f*32+k)*16+o)*32+i  (R5 layout)
    int i = a & 31, o = (a >> 5) & 15, s = a >> 9;
    int f = s >> 5, k = s & 31;
    B11[a] = (unsigned short)f2bf(w11[k*1536 + (o*32+i)*3 + f]);
  } else if (idx < 102400) {
    int a = idx - 98304;                   // W2H: [p][b][a]
    int p = a >> 10, rem = a & 1023;
    int b = rem >> 5, aa = rem & 31;
    const float* w2p = p==0?w2_00 : p==1?w2_01 : p==2?w2_10 : w2_11;
    W2H[a] = (unsigned short)f2bf(w2p[aa*32 + b]);
  } else if (idx < 106496) {
    int a = idx - 102400;                  // W2L
    int p = a >> 10, rem = a & 1023;
    int b = rem >> 5, aa = rem & 31;
    const float* w2p = p==0?w2_00 : p==1?w2_01 : p==2?w2_10 : w2_11;
    float v = w2p[aa*32 + b];
    short h = f2bf(v);
    W2L[a] = (unsigned short)f2bf(v - b2f(h));
  }
}

// ---------------------------------------------------------------------------
// Kernel 2: MFMA edge kernel — R5 structure (wave = 16 edges, 4 waves/block)
// with ONE change: radial-MLP layer2 via split-precision MFMA instead of the
// per-lane scalar w2 stream. x2L slot map identical to R5 ([t][wid][p][e]),
// stride 260. Everything else (F1 loops, P11 f-plane loop, stores) = R5.
// ---------------------------------------------------------------------------
struct EP {
  const float *r; const int *esrc;
  const float *b00, *b01, *b10, *b11;
  const float *w1_00, *b1_00, *b2_00;
  const float *w1_01, *b1_01, *b2_01;
  const float *w1_10, *b1_10, *b2_10;
  const float *w1_11, *b1_11, *b2_11;
  const unsigned short *B00, *B01, *B10, *B11, *W2H, *W2L;
  const float *h0c, *h1c;
  float *agg0, *agg1;
};

__global__ __launch_bounds__(256) void edge_mfma(EP P)
{
  __shared__ float x2L[32*260];   // [t][wid(4)][p(4)][e(16)], stride 260

  const int tid  = threadIdx.x;
  const int wid  = tid >> 6;
  const int lane = tid & 63;
  const int el   = lane & 15;
  const int kg   = lane >> 4;
  const int kg4  = kg << 2;
  const int eb   = blockIdx.x * 64 + wid * 16;
  const int e    = eb + el;
  const int isl  = kg * 8;

  const int   sidx = P.esrc[e];
  const float rv   = P.r[e];

  const f32x4 zero4 = {0.f, 0.f, 0.f, 0.f};

  // ---- radial MLPs via split-precision MFMA (replaces R5 scalar MLP) ----
  #pragma unroll
  for (int p = 0; p < 4; ++p) {
    const float* w1p = p==0?P.w1_00 : p==1?P.w1_01 : p==2?P.w1_10 : P.w1_11;
    const float* b1p = p==0?P.b1_00 : p==1?P.b1_01 : p==2?P.b1_10 : P.b1_11;
    const float* b2p = p==0?P.b2_00 : p==1?P.b2_01 : p==2?P.b2_10 : P.b2_11;
    const unsigned short* w2hp = P.W2H + p*1024;
    const unsigned short* w2lp = P.W2L + p*1024;
    f32x4 wa  = *(const f32x4*)(w1p + isl);
    f32x4 wb  = *(const f32x4*)(w1p + isl + 4);
    f32x4 ba  = *(const f32x4*)(b1p + isl);
    f32x4 bbv = *(const f32x4*)(b1p + isl + 4);
    bf16x8 bh0 = *(const bf16x8*)(w2hp + el*32 + isl);
    bf16x8 bh1 = *(const bf16x8*)(w2hp + (16+el)*32 + isl);
    bf16x8 bl0 = *(const bf16x8*)(w2lp + el*32 + isl);
    bf16x8 bl1 = *(const bf16x8*)(w2lp + (16+el)*32 + isl);
    float b2v0 = b2p[el];
    float b2v1 = b2p[16 + el];
    bf16x8 axh, axl;
    #pragma unroll
    for (int j = 0; j < 4; ++j) {
      float v0 = fmaxf(fmaf(rv, wa[j], ba[j]),  0.f);
      float v1 = fmaxf(fmaf(rv, wb[j], bbv[j]), 0.f);
      short h0s = f2bf(v0), h1s_ = f2bf(v1);
      axh[j]   = h0s;  axl[j]   = f2bf(v0 - b2f(h0s));
      axh[j+4] = h1s_; axl[j+4] = f2bf(v1 - b2f(h1s_));
    }
    f32x4 z0 = __builtin_amdgcn_mfma_f32_16x16x32_bf16(axl, bh0, zero4, 0,0,0);
    z0 = __builtin_amdgcn_mfma_f32_16x16x32_bf16(axh, bl0, z0, 0,0,0);
    z0 = __builtin_amdgcn_mfma_f32_16x16x32_bf16(axh, bh0, z0, 0,0,0);
    f32x4 z1 = __builtin_amdgcn_mfma_f32_16x16x32_bf16(axl, bh1, zero4, 0,0,0);
    z1 = __builtin_amdgcn_mfma_f32_16x16x32_bf16(axh, bl1, z1, 0,0,0);
    z1 = __builtin_amdgcn_mfma_f32_16x16x32_bf16(axh, bh1, z1, 0,0,0);
    f32x4 xv0, xv1;
    #pragma unroll
    for (int j = 0; j < 4; ++j) {
      xv0[j] = fmaxf(z0[j] + b2v0, 0.f);   // x2[edge kg4+j][ch el]
      xv1[j] = fmaxf(z1[j] + b2v1, 0.f);   // x2[edge kg4+j][ch 16+el]
    }
    *(f32x4*)&x2L[el*260      + wid*64 + p*16 + kg4] = xv0;
    *(f32x4*)&x2L[(16+el)*260 + wid*64 + p*16 + kg4] = xv1;
  }
  // no barrier: producers/consumers are in the same wave (in-order LDS)

  // ---- A-side feature slices (R5 verbatim) ----
  f32x4 h0a = *(const f32x4*)(P.h0c + (size_t)sidx*32 + isl);
  f32x4 h0b = *(const f32x4*)(P.h0c + (size_t)sidx*32 + isl + 4);
  float h1sl[24];
  {
    const float* hp = P.h1c + (size_t)sidx*96 + isl*3;
    #pragma unroll
    for (int q = 0; q < 6; ++q) {
      f32x4 v = *(const f32x4*)(hp + q*4);
      h1sl[q*4+0]=v[0]; h1sl[q*4+1]=v[1]; h1sl[q*4+2]=v[2]; h1sl[q*4+3]=v[3];
    }
  }

  bf16x8 a_h0;
  #pragma unroll
  for (int j = 0; j < 4; ++j) { a_h0[j] = f2bf(h0a[j]); a_h0[j+4] = f2bf(h0b[j]); }

  const int xrow = wid*64 + kg4;   // + p*16 -> slot of x2_p[edge kg4+r]

  // ---------------- P00: msg0 = b00 * (R00 . hs0) ----------------
  f32x4 macc0 = zero4;
  {
    const unsigned short* bb = P.B00 + el*32 + isl;
    #pragma unroll 4
    for (int t = 0; t < 32; ++t) {
      bf16x8 bv = *(const bf16x8*)(bb + t*512);
      f32x4 z = __builtin_amdgcn_mfma_f32_16x16x32_bf16(a_h0, bv, zero4, 0, 0, 0);
      f32x4 xs = *(const f32x4*)&x2L[t*260 + xrow + 0];     // path 0
      macc0[0] = fmaf(xs[0], z[0], macc0[0]);
      macc0[1] = fmaf(xs[1], z[1], macc0[1]);
      macc0[2] = fmaf(xs[2], z[2], macc0[2]);
      macc0[3] = fmaf(xs[3], z[3], macc0[3]);
    }
  }
  { // scale by b00 per C-row edge (e = eb + kg4 + r)
    f32x4 bv = *(const f32x4*)(P.b00 + eb + kg4);
    macc0[0]*=bv[0]; macc0[1]*=bv[1]; macc0[2]*=bv[2]; macc0[3]*=bv[3];
  }

  // ---------------- P10: msg0 += R10 . t10 ----------------
  {
    const float* bp = P.b10 + (size_t)e*3;
    float c0 = bp[0], c1 = bp[1], c2 = bp[2];
    bf16x8 a_t;
    #pragma unroll
    for (int j = 0; j < 8; ++j)
      a_t[j] = f2bf(c0*h1sl[j*3+0] + c1*h1sl[j*3+1] + c2*h1sl[j*3+2]);
    const unsigned short* bb = P.B10 + el*32 + isl;
    #pragma unroll 4
    for (int t = 0; t < 32; ++t) {
      bf16x8 bv = *(const bf16x8*)(bb + t*512);
      f32x4 z = __builtin_amdgcn_mfma_f32_16x16x32_bf16(a_t, bv, zero4, 0, 0, 0);
      f32x4 xs = *(const f32x4*)&x2L[t*260 + xrow + 32];    // path 2
      macc0[0] = fmaf(xs[0], z[0], macc0[0]);
      macc0[1] = fmaf(xs[1], z[1], macc0[1]);
      macc0[2] = fmaf(xs[2], z[2], macc0[2]);
      macc0[3] = fmaf(xs[3], z[3], macc0[3]);
    }
  }
  // store msg0 mean over 8 edges per dst
  {
    float s = macc0[0]+macc0[1]+macc0[2]+macc0[3];
    s += __shfl_xor(s, 16);
    if ((kg & 1) == 0)
      P.agg0[(size_t)((eb >> 3) + (kg >> 1))*16 + el] = s * 0.125f;
  }

  // ---------------- P01: msg1 = b01[m] * (R01 . hs0) ----------------
  f32x4 c01 = zero4;
  {
    const unsigned short* bb = P.B01 + el*32 + isl;
    #pragma unroll 4
    for (int t = 0; t < 32; ++t) {
      bf16x8 bv = *(const bf16x8*)(bb + t*512);
      f32x4 z = __builtin_amdgcn_mfma_f32_16x16x32_bf16(a_h0, bv, zero4, 0, 0, 0);
      f32x4 xs = *(const f32x4*)&x2L[t*260 + xrow + 16];    // path 1
      c01[0] = fmaf(xs[0], z[0], c01[0]);
      c01[1] = fmaf(xs[1], z[1], c01[1]);
      c01[2] = fmaf(xs[2], z[2], c01[2]);
      c01[3] = fmaf(xs[3], z[3], c01[3]);
    }
  }
  f32x4 m1a, m1b, m1c;
  {
    const float* bp = P.b01 + (size_t)(eb + kg4)*3;   // 12 floats: rows kg4..kg4+3
    f32x4 q0 = *(const f32x4*)(bp);
    f32x4 q1 = *(const f32x4*)(bp + 4);
    f32x4 q2 = *(const f32x4*)(bp + 8);
    m1a[0]=c01[0]*q0[0]; m1a[1]=c01[1]*q0[3]; m1a[2]=c01[2]*q1[2]; m1a[3]=c01[3]*q2[1];
    m1b[0]=c01[0]*q0[1]; m1b[1]=c01[1]*q1[0]; m1b[2]=c01[2]*q1[3]; m1b[3]=c01[3]*q2[2];
    m1c[0]=c01[0]*q0[2]; m1c[1]=c01[1]*q1[1]; m1c[2]=c01[2]*q2[0]; m1c[3]=c01[3]*q2[3];
  }

  // ---------------- P11: msg1 += sum_f R11f . tmp_f (R5 structure) --------
  {
    const float* b11e = P.b11 + (size_t)e*27;
    #pragma unroll 1
    for (int f = 0; f < 3; ++f) {
      float bm[9];
      #pragma unroll
      for (int mn = 0; mn < 9; ++mn) bm[mn] = b11e[mn*3 + f];
      bf16x8 am0, am1, am2;
      #pragma unroll
      for (int j = 0; j < 8; ++j) {
        float hn0 = h1sl[j*3+0], hn1 = h1sl[j*3+1], hn2 = h1sl[j*3+2];
        am0[j] = f2bf(bm[0]*hn0 + bm[1]*hn1 + bm[2]*hn2);
        am1[j] = f2bf(bm[3]*hn0 + bm[4]*hn1 + bm[5]*hn2);
        am2[j] = f2bf(bm[6]*hn0 + bm[7]*hn1 + bm[8]*hn2);
      }
      const unsigned short* bb = P.B11 + (size_t)f*16384 + el*32 + isl;
      #pragma unroll 4
      for (int t = 0; t < 32; ++t) {
        bf16x8 bv = *(const bf16x8*)(bb + t*512);
        f32x4 z0 = __builtin_amdgcn_mfma_f32_16x16x32_bf16(am0, bv, zero4, 0, 0, 0);
        f32x4 z1 = __builtin_amdgcn_mfma_f32_16x16x32_bf16(am1, bv, zero4, 0, 0, 0);
        f32x4 z2 = __builtin_amdgcn_mfma_f32_16x16x32_bf16(am2, bv, zero4, 0, 0, 0);
        f32x4 xs = *(const f32x4*)&x2L[t*260 + xrow + 48];  // path 3
        m1a[0] = fmaf(xs[0], z0[0], m1a[0]);
        m1a[1] = fmaf(xs[1], z0[1], m1a[1]);
        m1a[2] = fmaf(xs[2], z0[2], m1a[2]);
        m1a[3] = fmaf(xs[3], z0[3], m1a[3]);
        m1b[0] = fmaf(xs[0], z1[0], m1b[0]);
        m1b[1] = fmaf(xs[1], z1[1], m1b[1]);
        m1b[2] = fmaf(xs[2], z1[2], m1b[2]);
        m1b[3] = fmaf(xs[3], z1[3], m1b[3]);
        m1c[0] = fmaf(xs[0], z2[0], m1c[0]);
        m1c[1] = fmaf(xs[1], z2[1], m1c[1]);
        m1c[2] = fmaf(xs[2], z2[2], m1c[2]);
        m1c[3] = fmaf(xs[3], z2[3], m1c[3]);
      }
    }
  }

  // store msg1 mean over 8 edges per dst
  {
    float sa = m1a[0]+m1a[1]+m1a[2]+m1a[3]; sa += __shfl_xor(sa, 16);
    float sb = m1b[0]+m1b[1]+m1b[2]+m1b[3]; sb += __shfl_xor(sb, 16);
    float sc = m1c[0]+m1c[1]+m1c[2]+m1c[3]; sc += __shfl_xor(sc, 16);
    if ((kg & 1) == 0) {
      float* p = P.agg1 + (size_t)((eb >> 3) + (kg >> 1))*48 + el*3;
      p[0] = sa * 0.125f; p[1] = sb * 0.125f; p[2] = sc * 0.125f;
    }
  }
}

// ---------------------------------------------------------------------------
// Kernel 3: self-interaction + GNormSE3, 4 lanes per node (R5, passing).
// ---------------------------------------------------------------------------
__global__ __launch_bounds__(256) void gnorm_kernel(
    const float* __restrict__ agg0, const float* __restrict__ agg1,
    const float* __restrict__ h0c, const float* __restrict__ h1c,
    const float* __restrict__ ws0, const float* __restrict__ ws1,
    const float* __restrict__ g0, const float* __restrict__ be0,
    const float* __restrict__ g1, const float* __restrict__ be1,
    float* __restrict__ out)
{
  const int gt  = blockIdx.x * 256 + threadIdx.x;
  const int fi  = gt >> 2;
  const int t4  = gt & 3;
  const int ob  = t4 * 4;

  const float* h0p = h0c + (size_t)fi*32;
  const float* h1p = h1c + (size_t)fi*96;

  float o0[4];
  #pragma unroll
  for (int oo = 0; oo < 4; ++oo) {
    int o = ob + oo;
    float a = agg0[(size_t)fi*16 + o];
    #pragma unroll
    for (int i = 0; i < 32; ++i)
      a = fmaf(ws0[o*32+i], h0p[i], a);
    o0[oo] = a;
  }
  {
    float n0[4], lmu = 0.f;
    #pragma unroll
    for (int oo = 0; oo < 4; ++oo) { n0[oo] = sqrtf(fmaf(o0[oo], o0[oo], 1e-12f)); lmu += n0[oo]; }
    lmu += __shfl_xor(lmu, 1); lmu += __shfl_xor(lmu, 2);
    float mu = lmu * 0.0625f;
    float lv = 0.f;
    #pragma unroll
    for (int oo = 0; oo < 4; ++oo) { float d = n0[oo]-mu; lv = fmaf(d, d, lv); }
    lv += __shfl_xor(lv, 1); lv += __shfl_xor(lv, 2);
    float inv = 1.f / sqrtf(lv * 0.0625f + 1e-5f);
    #pragma unroll
    for (int oo = 0; oo < 4; ++oo) {
      int o = ob + oo;
      float t = fmaxf(fmaf((n0[oo]-mu)*inv, g0[o], be0[o]), 0.f);
      out[(size_t)fi*16 + o] = t * (o0[oo] / n0[oo]);
    }
  }

  float o1[12];
  #pragma unroll
  for (int oo = 0; oo < 4; ++oo) {
    int o = ob + oo;
    float a0 = agg1[(size_t)fi*48 + o*3+0];
    float a1 = agg1[(size_t)fi*48 + o*3+1];
    float a2 = agg1[(size_t)fi*48 + o*3+2];
    #pragma unroll
    for (int i = 0; i < 32; ++i) {
      float wv = ws1[o*32+i];
      a0 = fmaf(wv, h1p[i*3+0], a0);
      a1 = fmaf(wv, h1p[i*3+1], a1);
      a2 = fmaf(wv, h1p[i*3+2], a2);
    }
    o1[oo*3+0] = a0; o1[oo*3+1] = a1; o1[oo*3+2] = a2;
  }
  {
    float n1[4], lmu = 0.f;
    #pragma unroll
    for (int oo = 0; oo < 4; ++oo) {
      float s = fmaf(o1[oo*3+0], o1[oo*3+0], 1e-12f);
      s = fmaf(o1[oo*3+1], o1[oo*3+1], s);
      s = fmaf(o1[oo*3+2], o1[oo*3+2], s);
      n1[oo] = sqrtf(s); lmu += n1[oo];
    }
    lmu += __shfl_xor(lmu, 1); lmu += __shfl_xor(lmu, 2);
    float mu = lmu * 0.0625f;
    float lv = 0.f;
    #pragma unroll
    for (int oo = 0; oo < 4; ++oo) { float d = n1[oo]-mu; lv = fmaf(d, d, lv); }
    lv += __shfl_xor(lv, 1); lv += __shfl_xor(lv, 2);
    float inv = 1.f / sqrtf(lv * 0.0625f + 1e-5f);
    float* out1 = out + (size_t)BN*16;
    #pragma unroll
    for (int oo = 0; oo < 4; ++oo) {
      int o = ob + oo;
      float t = fmaxf(fmaf((n1[oo]-mu)*inv, g1[o], be1[o]), 0.f);
      #pragma unroll
      for (int m = 0; m < 3; ++m)
        out1[(size_t)fi*48 + o*3+m] = t * (o1[oo*3+m] / n1[oo]);
    }
  }
}

// ---------------------------------------------------------------------------
extern "C" void kernel_launch(void* const* d_in, const int* in_sizes, int n_in,
                              void* d_out, int out_size, void* d_ws, size_t ws_size,
                              hipStream_t stream)
{
  (void)in_sizes; (void)n_in; (void)out_size; (void)ws_size;
  const float* h0   = (const float*)d_in[0];
  const float* h1   = (const float*)d_in[1];
  const float* uph0 = (const float*)d_in[2];
  const float* uph1 = (const float*)d_in[3];
  const float* xyz  = (const float*)d_in[4];
  const float* xyzp = (const float*)d_in[5];
  const int*   esrc = (const int*)d_in[6];
  // d_in[7] = edge_dst: structurally e>>3; not needed.
  const float* rr   = (const float*)d_in[8];

  float* wsp  = (float*)d_ws;
  float* h0c  = wsp;                          // BN*32
  float* h1c  = h0c + (size_t)BN*32;          // BN*96
  float* agg0 = h1c + (size_t)BN*96;          // BN*16
  float* agg1 = agg0 + (size_t)BN*16;         // BN*48
  unsigned short* B00 = (unsigned short*)(agg1 + (size_t)BN*48);
  unsigned short* B01 = B00 + 16384;
  unsigned short* B10 = B01 + 16384;
  unsigned short* B11 = B10 + 16384;          // 49152
  unsigned short* W2H = B11 + 49152;          // 4096
  unsigned short* W2L = W2H + 4096;           // 4096

  interp_kernel<<<BN/4, 256, 0, stream>>>(h0, h1, uph0, uph1, xyz, xyzp, h0c, h1c);
  repack_bf16<<<416, 256, 0, stream>>>(
      (const float*)d_in[17], (const float*)d_in[22],
      (const float*)d_in[27], (const float*)d_in[32],
      (const float*)d_in[15], (const float*)d_in[20],
      (const float*)d_in[25], (const float*)d_in[30],
      B00, B01, B10, B11, W2H, W2L);

  EP P;
  P.r = rr; P.esrc = esrc;
  P.b00 = (const float*)d_in[9];  P.b01 = (const float*)d_in[10];
  P.b10 = (const float*)d_in[11]; P.b11 = (const float*)d_in[12];
  P.w1_00 = (const float*)d_in[13]; P.b1_00 = (const float*)d_in[14]; P.b2_00 = (const float*)d_in[16];
  P.w1_01 = (const float*)d_in[18]; P.b1_01 = (const float*)d_in[19]; P.b2_01 = (const float*)d_in[21];
  P.w1_10 = (const float*)d_in[23]; P.b1_10 = (const float*)d_in[24]; P.b2_10 = (const float*)d_in[26];
  P.w1_11 = (const float*)d_in[28]; P.b1_11 = (const float*)d_in[29]; P.b2_11 = (const float*)d_in[31];
  P.B00 = B00; P.B01 = B01; P.B10 = B10; P.B11 = B11; P.W2H = W2H; P.W2L = W2L;
  P.h0c = h0c; P.h1c = h1c; P.agg0 = agg0; P.agg1 = agg1;

  edge_mfma<<<NE/64, 256, 0, stream>>>(P);

  gnorm_kernel<<<BN*4/256, 256, 0, stream>>>(agg0, agg1, h0c, h1c,
      (const float*)d_in[33], (const float*)d_in[34],
      (const float*)d_in[35], (const float*)d_in[36],
      (const float*)d_in[37], (const float*)d_in[38],
      (float*)d_out);
}